// Round 2
// baseline (1223.282 us; speedup 1.0000x reference)
//
#include <hip/hip_runtime.h>
#include <hip/hip_bf16.h>

#define NN 100000
#define EE 1600000
#define RRR 4
#define HHH 8
#define NT 400000      // RRR * NN
#define SCANB 782      // ceil(NT / 512)

typedef unsigned int u32;
typedef unsigned short u16;

// ---------------- workspace layout (bytes), total ~152.6 MB ----------------
static constexpr size_t OFF_KV   = 0;              // u32 [N][64] packed (bf16 K | bf16 V<<16), per-relation reuse
static constexpr size_t OFF_Q    = 25600000;       // bf16 [4][N][64] Q; ALIASED by 'stacked' bf16 [4][N][64] after gathers
static constexpr size_t OFF_S    = 76800000;       // bf16 [4][N][64] V-sums
static constexpr size_t OFF_AL   = 128000000;      // f32  [4][N][8] energy sums
static constexpr size_t OFF_PW   = 140800000;      // f32  [2][17][4096] packed weights
static constexpr size_t OFF_PART = 141357056;      // float2 [32][32] softmax partials
static constexpr size_t OFF_FIN  = 141365248;      // float2 [32]
static constexpr size_t OFF_CNT  = 141365504;      // u32 [NT]
static constexpr size_t OFF_ROWP = 142965504;      // u32 [NT+1] (+pad)
static constexpr size_t OFF_CUR  = 144565520;      // u32 [NT]
static constexpr size_t OFF_EDG  = 146165520;      // u32 [E] src only (relation implicit in segment)
static constexpr size_t OFF_BS   = 152565520;      // u32 [SCANB]

__device__ inline u16 f2bf(float f){
  union { __hip_bfloat16 h; u16 u; } cv; cv.h = __float2bfloat16(f); return cv.u;
}
__device__ inline float bf2f(u16 u){ return __uint_as_float(((u32)u) << 16); }

__device__ inline void store4(float* p, float a, float b, float c, float d){
  float4 v; v.x = a; v.y = b; v.z = c; v.w = d; *(float4*)p = v;
}
__device__ inline void store4(__hip_bfloat16* p, float a, float b, float c, float d){
  ushort4 v; v.x = f2bf(a); v.y = f2bf(b); v.z = f2bf(c); v.w = f2bf(d); *(ushort4*)p = v;
}

// ---------------- zero fill (replaces hipMemsetAsync) ----------------
__global__ __launch_bounds__(256) void k_zero(u32* __restrict__ a, u32* __restrict__ b){
  int i = blockIdx.x * 256 + threadIdx.x;
  if (i < NT){ a[i] = 0u; b[i] = 0u; }
}

// ---------------- CSR build, segmented by (relation, dst) ----------------
__global__ __launch_bounds__(256) void k_hist(const int* __restrict__ dst, const int* __restrict__ typ,
                                              u32* __restrict__ cnt){
  for (int e = blockIdx.x * blockDim.x + threadIdx.x; e < EE; e += gridDim.x * blockDim.x)
    atomicAdd(&cnt[typ[e] * NN + dst[e]], 1u);
}

__global__ __launch_bounds__(512) void k_scan1(const u32* __restrict__ cnt, u32* __restrict__ rowp,
                                               u32* __restrict__ bsum){
  __shared__ u32 tmp[512];
  int t = threadIdx.x;
  int i = blockIdx.x * 512 + t;
  u32 v = (i < NT) ? cnt[i] : 0u;
  tmp[t] = v; __syncthreads();
  for (int off = 1; off < 512; off <<= 1){
    u32 add = (t >= off) ? tmp[t - off] : 0u; __syncthreads();
    tmp[t] += add; __syncthreads();
  }
  if (i < NT) rowp[i] = tmp[t] - v;        // block-local exclusive
  if (t == 511) bsum[blockIdx.x] = tmp[t];
}

__global__ __launch_bounds__(1024) void k_scan2(u32* __restrict__ bsum, u32* __restrict__ rowp){
  __shared__ u32 tmp[1024];
  int t = threadIdx.x;
  u32 v = (t < SCANB) ? bsum[t] : 0u;
  tmp[t] = v; __syncthreads();
  for (int off = 1; off < 1024; off <<= 1){
    u32 add = (t >= off) ? tmp[t - off] : 0u; __syncthreads();
    tmp[t] += add; __syncthreads();
  }
  if (t < SCANB) bsum[t] = tmp[t] - v;     // exclusive block offsets
  if (t == 0) rowp[NT] = EE;
}

__global__ __launch_bounds__(512) void k_scan3(u32* __restrict__ rowp, const u32* __restrict__ bsum){
  int i = blockIdx.x * 512 + threadIdx.x;
  if (i < NT) rowp[i] += bsum[blockIdx.x];
}

__global__ __launch_bounds__(256) void k_scatter(const int* __restrict__ src, const int* __restrict__ dst,
                                                 const int* __restrict__ typ, const u32* __restrict__ rowp,
                                                 u32* __restrict__ cur, u32* __restrict__ edges){
  for (int e = blockIdx.x * blockDim.x + threadIdx.x; e < EE; e += gridDim.x * blockDim.x){
    int seg = typ[e] * NN + dst[e];
    u32 pos = rowp[seg] + atomicAdd(&cur[seg], 1u);
    edges[pos] = (u32)src[e];
  }
}

// ---------------- weight repack (both layers): pw[l][mat][c][hd] ----------------
// mats 0-3 Q r0-3 ; 4-7 K ; 8-11 V ; 12 W_self ; 13-16 Wcat r0-3
__global__ __launch_bounds__(256) void k_repack(const float* __restrict__ WQ, const float* __restrict__ WK,
                                                const float* __restrict__ WV, const float* __restrict__ Wcat,
                                                const float* __restrict__ Wself, float* __restrict__ pw){
  int t = blockIdx.x * 256 + threadIdx.x;
  if (t >= 2 * 17 * 4096) return;
  int l = t / (17 * 4096), rem = t % (17 * 4096);
  int mat = rem >> 12, idx = rem & 4095;
  int c = idx >> 6, hd = idx & 63;
  float v;
  if (mat < 12){
    int kind = mat >> 2, r = mat & 3;
    int h = hd >> 3, d = hd & 7;
    const float* Wsrc = (kind == 0) ? WQ : (kind == 1) ? WK : WV;
    v = Wsrc[((((l * RRR + r) * HHH + h) * 64) + c) * 8 + d];
  } else if (mat == 12){
    v = Wself[(l * 64 + c) * 64 + hd];
  } else {
    int r = mat - 13;
    v = Wcat[(((l * RRR + r) * 64) + c) * 64 + hd];
  }
  pw[t] = v;
}

// ---------------- generic N x 64 @ 64 x 64 GEMM (mat = blockIdx.y) ----------------
template<typename OutT>
__global__ __launch_bounds__(256) void k_gemm64(const float* __restrict__ Abase, long strideA,
                                                const float* __restrict__ Wp,
                                                OutT* __restrict__ Obase, long strideO){
  __shared__ float At[64][64];
  __shared__ float Wl[64][64];
  int mat = blockIdx.y;
  const float* A = Abase + (long)mat * strideA;
  const float* W = Wp + mat * 4096;
  OutT* O = Obase + (long)mat * strideO;
  int t = threadIdx.x;
  int n0 = blockIdx.x * 64;
  {
    const float4* w4 = (const float4*)W;
    float4* l4 = (float4*)(&Wl[0][0]);
    #pragma unroll
    for (int i = 0; i < 4; i++) l4[t + 256 * i] = w4[t + 256 * i];
  }
  {
    int nl = t & 63, cq = (t >> 6) * 16;
    int n = n0 + nl;
    #pragma unroll
    for (int j = 0; j < 4; j++){
      float4 v; v.x = v.y = v.z = v.w = 0.f;
      if (n < NN) v = *(const float4*)(A + (long)n * 64 + cq + j * 4);
      At[cq + j * 4 + 0][nl] = v.x; At[cq + j * 4 + 1][nl] = v.y;
      At[cq + j * 4 + 2][nl] = v.z; At[cq + j * 4 + 3][nl] = v.w;
    }
  }
  __syncthreads();
  int nl4 = (t & 15) * 4;
  int h4  = (t >> 4) * 4;
  float acc[4][4] = {};
  #pragma unroll 4
  for (int c = 0; c < 64; c++){
    float4 av = *(const float4*)(&At[c][nl4]);
    float4 wv = *(const float4*)(&Wl[c][h4]);
    acc[0][0] += av.x * wv.x; acc[0][1] += av.x * wv.y; acc[0][2] += av.x * wv.z; acc[0][3] += av.x * wv.w;
    acc[1][0] += av.y * wv.x; acc[1][1] += av.y * wv.y; acc[1][2] += av.y * wv.z; acc[1][3] += av.y * wv.w;
    acc[2][0] += av.z * wv.x; acc[2][1] += av.z * wv.y; acc[2][2] += av.z * wv.z; acc[2][3] += av.z * wv.w;
    acc[3][0] += av.w * wv.x; acc[3][1] += av.w * wv.y; acc[3][2] += av.w * wv.z; acc[3][3] += av.w * wv.w;
  }
  #pragma unroll
  for (int i = 0; i < 4; i++){
    int n = n0 + nl4 + i;
    if (n < NN) store4(&O[(long)n * 64 + h4], acc[i][0], acc[i][1], acc[i][2], acc[i][3]);
  }
}

// ---------------- K,V GEMM for one relation, packed u32 output ----------------
__global__ __launch_bounds__(256) void k_gemmKV(const float* __restrict__ A,
                                                const float* __restrict__ pwK, const float* __restrict__ pwV,
                                                u32* __restrict__ kvp){
  __shared__ float At[64][64];
  __shared__ float Wk[64][64];
  __shared__ float Wv[64][64];
  int t = threadIdx.x;
  int n0 = blockIdx.x * 64;
  {
    const float4* wk4 = (const float4*)pwK;
    const float4* wv4 = (const float4*)pwV;
    float4* lk = (float4*)(&Wk[0][0]);
    float4* lv = (float4*)(&Wv[0][0]);
    #pragma unroll
    for (int i = 0; i < 4; i++){ lk[t + 256 * i] = wk4[t + 256 * i]; lv[t + 256 * i] = wv4[t + 256 * i]; }
  }
  {
    int nl = t & 63, cq = (t >> 6) * 16;
    int n = n0 + nl;
    #pragma unroll
    for (int j = 0; j < 4; j++){
      float4 v; v.x = v.y = v.z = v.w = 0.f;
      if (n < NN) v = *(const float4*)(A + (long)n * 64 + cq + j * 4);
      At[cq + j * 4 + 0][nl] = v.x; At[cq + j * 4 + 1][nl] = v.y;
      At[cq + j * 4 + 2][nl] = v.z; At[cq + j * 4 + 3][nl] = v.w;
    }
  }
  __syncthreads();
  int nl4 = (t & 15) * 4;
  int h4  = (t >> 4) * 4;
  float aK[4][4] = {}, aV[4][4] = {};
  #pragma unroll 4
  for (int c = 0; c < 64; c++){
    float4 av = *(const float4*)(&At[c][nl4]);
    float4 wk = *(const float4*)(&Wk[c][h4]);
    float4 wv = *(const float4*)(&Wv[c][h4]);
    aK[0][0] += av.x * wk.x; aK[0][1] += av.x * wk.y; aK[0][2] += av.x * wk.z; aK[0][3] += av.x * wk.w;
    aK[1][0] += av.y * wk.x; aK[1][1] += av.y * wk.y; aK[1][2] += av.y * wk.z; aK[1][3] += av.y * wk.w;
    aK[2][0] += av.z * wk.x; aK[2][1] += av.z * wk.y; aK[2][2] += av.z * wk.z; aK[2][3] += av.z * wk.w;
    aK[3][0] += av.w * wk.x; aK[3][1] += av.w * wk.y; aK[3][2] += av.w * wk.z; aK[3][3] += av.w * wk.w;
    aV[0][0] += av.x * wv.x; aV[0][1] += av.x * wv.y; aV[0][2] += av.x * wv.z; aV[0][3] += av.x * wv.w;
    aV[1][0] += av.y * wv.x; aV[1][1] += av.y * wv.y; aV[1][2] += av.y * wv.z; aV[1][3] += av.y * wv.w;
    aV[2][0] += av.z * wv.x; aV[2][1] += av.z * wv.y; aV[2][2] += av.z * wv.z; aV[2][3] += av.z * wv.w;
    aV[3][0] += av.w * wv.x; aV[3][1] += av.w * wv.y; aV[3][2] += av.w * wv.z; aV[3][3] += av.w * wv.w;
  }
  #pragma unroll
  for (int i = 0; i < 4; i++){
    int n = n0 + nl4 + i;
    if (n < NN){
      uint4 pk;
      pk.x = (u32)f2bf(aK[i][0]) | ((u32)f2bf(aV[i][0]) << 16);
      pk.y = (u32)f2bf(aK[i][1]) | ((u32)f2bf(aV[i][1]) << 16);
      pk.z = (u32)f2bf(aK[i][2]) | ((u32)f2bf(aV[i][2]) << 16);
      pk.w = (u32)f2bf(aK[i][3]) | ((u32)f2bf(aV[i][3]) << 16);
      *(uint4*)(&kvp[(long)n * 64 + h4]) = pk;
    }
  }
}

// ---------------- edge gather for one relation: 1 wave per dst node ----------------
__global__ __launch_bounds__(256) void k_gather(const u32* __restrict__ edges, const u32* __restrict__ rowpR,
                                                const u32* __restrict__ kvp, const u16* __restrict__ Qr,
                                                u16* __restrict__ Sr, float* __restrict__ alphaR){
  int wid = threadIdx.x >> 6, lane = threadIdx.x & 63;
  int n = blockIdx.x * 4 + wid;
  float q = bf2f(Qr[(long)n * 64 + lane]);
  u32 beg = rowpR[n], end = rowpR[n + 1];
  float sa = 0.f, aa = 0.f;
  for (u32 i = beg; i < end; ++i){
    int s = (int)edges[i];
    u32 w = kvp[(long)s * 64 + lane];
    float kv = bf2f((u16)(w & 0xFFFFu));
    float vv = bf2f((u16)(w >> 16));
    float p = q * kv;
    p += __shfl_xor(p, 1);
    p += __shfl_xor(p, 2);
    p += __shfl_xor(p, 4);
    float e = p * 0.35355339059327373f;   // 1/sqrt(8)
    e = (e > 0.f) ? e : 0.01f * e;        // leaky_relu
    aa += e;
    sa += vv;
  }
  Sr[(long)n * 64 + lane] = f2bf(sa);
  if ((lane & 7) == 0) alphaR[(long)n * 8 + (lane >> 3)] = aa;
}

// ---------------- column softmax stats over N per (r,h) ----------------
__global__ __launch_bounds__(256) void k_stats1(const float* __restrict__ alpha, float2* __restrict__ part){
  int col = blockIdx.x;            // r*8+h
  int r = col >> 3, h = col & 7;
  int chunk = blockIdx.y;
  const int per = (NN + 31) / 32;
  int nbeg = chunk * per;
  int nend = nbeg + per; if (nend > NN) nend = NN;
  int t = threadIdx.x;
  float m = -1e30f, s = 0.f;
  for (int n = nbeg + t; n < nend; n += 256){
    float a = alpha[((long)r * NN + n) * 8 + h];
    if (a > m){ s *= expf(m - a); m = a; }
    s += expf(a - m);
  }
  __shared__ float sm[256], ss[256];
  sm[t] = m; ss[t] = s; __syncthreads();
  for (int off = 128; off > 0; off >>= 1){
    if (t < off){
      float m2 = sm[t + off], s2 = ss[t + off];
      float M = fmaxf(sm[t], m2);
      ss[t] = ss[t] * expf(sm[t] - M) + s2 * expf(m2 - M);
      sm[t] = M;
    }
    __syncthreads();
  }
  if (t == 0) part[col * 32 + chunk] = make_float2(sm[0], ss[0]);
}

__global__ void k_stats2(const float2* __restrict__ part, float2* __restrict__ fin){
  int col = threadIdx.x;
  if (col < 32){
    float M = -1e30f, S = 0.f;
    for (int i = 0; i < 32; i++){
      float2 p = part[col * 32 + i];
      float Mn = fmaxf(M, p.x);
      S = S * expf(M - Mn) + p.y * expf(p.x - Mn);
      M = Mn;
    }
    fin[col] = make_float2(M, 1.f / S);
  }
}

// ---------------- message GEMM with fused alpha apply: stacked[r] = (alpha ⊙ S[r]) @ Wcat[r] ----------------
__global__ __launch_bounds__(256) void k_msggemm(const u16* __restrict__ S, const float* __restrict__ alpha,
                                                 const float2* __restrict__ fin, const float* __restrict__ pwCat,
                                                 u16* __restrict__ stacked){
  __shared__ float At[64][64];
  __shared__ float Wl[64][64];
  int r = blockIdx.y;
  int t = threadIdx.x;
  int n0 = blockIdx.x * 64;
  {
    const float4* w4 = (const float4*)(pwCat + r * 4096);
    float4* l4 = (float4*)(&Wl[0][0]);
    #pragma unroll
    for (int i = 0; i < 4; i++) l4[t + 256 * i] = w4[t + 256 * i];
  }
  {
    int nl = t & 63, cq = (t >> 6) * 16;
    int n = n0 + nl;
    int na = (n < NN) ? n : (NN - 1);
    int h0 = cq >> 3;
    float2 f0 = fin[r * 8 + h0];
    float2 f1 = fin[r * 8 + h0 + 1];
    float a0 = alpha[((long)r * NN + na) * 8 + h0];
    float a1 = alpha[((long)r * NN + na) * 8 + h0 + 1];
    float w0 = expf(a0 - f0.x) * f0.y;
    float w1 = expf(a1 - f1.x) * f1.y;
    const u32* sp = (const u32*)(S + ((long)r * NN + na) * 64 + cq);
    #pragma unroll
    for (int jj = 0; jj < 8; jj++){
      u32 b = sp[jj];
      float wm = (jj < 4) ? w0 : w1;
      At[cq + jj * 2 + 0][nl] = bf2f((u16)(b & 0xFFFFu)) * wm;
      At[cq + jj * 2 + 1][nl] = bf2f((u16)(b >> 16)) * wm;
    }
  }
  __syncthreads();
  int nl4 = (t & 15) * 4;
  int h4  = (t >> 4) * 4;
  float acc[4][4] = {};
  #pragma unroll 4
  for (int c = 0; c < 64; c++){
    float4 av = *(const float4*)(&At[c][nl4]);
    float4 wv = *(const float4*)(&Wl[c][h4]);
    acc[0][0] += av.x * wv.x; acc[0][1] += av.x * wv.y; acc[0][2] += av.x * wv.z; acc[0][3] += av.x * wv.w;
    acc[1][0] += av.y * wv.x; acc[1][1] += av.y * wv.y; acc[1][2] += av.y * wv.z; acc[1][3] += av.y * wv.w;
    acc[2][0] += av.z * wv.x; acc[2][1] += av.z * wv.y; acc[2][2] += av.z * wv.z; acc[2][3] += av.z * wv.w;
    acc[3][0] += av.w * wv.x; acc[3][1] += av.w * wv.y; acc[3][2] += av.w * wv.z; acc[3][3] += av.w * wv.w;
  }
  #pragma unroll
  for (int i = 0; i < 4; i++){
    int n = n0 + nl4 + i;
    if (n < NN){
      ushort4 v;
      v.x = f2bf(acc[i][0]); v.y = f2bf(acc[i][1]); v.z = f2bf(acc[i][2]); v.w = f2bf(acc[i][3]);
      *(ushort4*)(&stacked[((long)r * NN + n) * 64 + h4]) = v;
    }
  }
}

// ---------------- semantic attn + fused self-GEMM + gelu + residual + LN ----------------
__global__ __launch_bounds__(256) void k_final(const u16* __restrict__ stacked, const float* __restrict__ xin,
                                               const float* __restrict__ pwSelf,
                                               const float* __restrict__ semw, const float* __restrict__ semb,
                                               const float* __restrict__ lng, const float* __restrict__ lnb,
                                               float* __restrict__ xout){
  __shared__ float Ws[64][64];
  __shared__ float xr[4][64];
  int t = threadIdx.x;
  int wid = t >> 6, lane = t & 63;
  int n = blockIdx.x * 4 + wid;
  {
    const float4* w4 = (const float4*)pwSelf;
    float4* l4 = (float4*)(&Ws[0][0]);
    #pragma unroll
    for (int i = 0; i < 4; i++) l4[t + 256 * i] = w4[t + 256 * i];
  }
  xr[wid][lane] = xin[(long)n * 64 + lane];
  __syncthreads();
  float selfv = 0.f;
  #pragma unroll 8
  for (int c = 0; c < 64; c++) selfv += xr[wid][c] * Ws[c][lane];
  float st[4];
  #pragma unroll
  for (int r = 0; r < 4; r++) st[r] = bf2f(stacked[((long)r * NN + n) * 64 + lane]);
  float sw = semw[lane];
  float lg[4];
  #pragma unroll
  for (int r = 0; r < 4; r++){
    float p = st[r] * sw;
    #pragma unroll
    for (int o = 1; o < 64; o <<= 1) p += __shfl_xor(p, o);
    lg[r] = p + semb[0];
  }
  float mx = fmaxf(fmaxf(lg[0], lg[1]), fmaxf(lg[2], lg[3]));
  float e0 = expf(lg[0] - mx), e1 = expf(lg[1] - mx), e2 = expf(lg[2] - mx), e3 = expf(lg[3] - mx);
  float inv = 1.f / (e0 + e1 + e2 + e3);
  float agg = (e0 * st[0] + e1 * st[1] + e2 * st[2] + e3 * st[3]) * inv;
  float pre = selfv + agg;
  float ge = 0.5f * pre * (1.f + erff(pre * 0.70710678118654752f));
  float y = xr[wid][lane] + ge;
  float mu = y;
  #pragma unroll
  for (int o = 1; o < 64; o <<= 1) mu += __shfl_xor(mu, o);
  mu *= (1.f / 64.f);
  float d = y - mu;
  float vv = d * d;
  #pragma unroll
  for (int o = 1; o < 64; o <<= 1) vv += __shfl_xor(vv, o);
  vv *= (1.f / 64.f);
  xout[(long)n * 64 + lane] = d * rsqrtf(vv + 1e-5f) * lng[lane] + lnb[lane];
}

extern "C" void kernel_launch(void* const* d_in, const int* in_sizes, int n_in,
                              void* d_out, int out_size, void* d_ws, size_t ws_size,
                              hipStream_t stream){
  const float* x0    = (const float*)d_in[0];
  const int*   eidx  = (const int*)d_in[1];
  const int*   etyp  = (const int*)d_in[2];
  const float* WQ    = (const float*)d_in[3];
  const float* WK    = (const float*)d_in[4];
  const float* WV    = (const float*)d_in[5];
  const float* Wcat  = (const float*)d_in[6];
  const float* semw  = (const float*)d_in[7];
  const float* semb  = (const float*)d_in[8];
  const float* Wself = (const float*)d_in[9];
  const float* lng   = (const float*)d_in[10];
  const float* lnb   = (const float*)d_in[11];
  float* out = (float*)d_out;
  char* ws = (char*)d_ws;

  const int* srcArr = eidx;        // edge_index row 0 = src (j)
  const int* dstArr = eidx + EE;   // row 1 = dst (i)

  u32*  kvp      = (u32*)(ws + OFF_KV);
  __hip_bfloat16* QbW = (__hip_bfloat16*)(ws + OFF_Q);
  u16*  Qb       = (u16*)(ws + OFF_Q);
  u16*  stackedB = (u16*)(ws + OFF_Q);     // aliases dead Q after gathers
  u16*  Sb       = (u16*)(ws + OFF_S);
  float* alphaB  = (float*)(ws + OFF_AL);
  float* pw      = (float*)(ws + OFF_PW);
  float2* part   = (float2*)(ws + OFF_PART);
  float2* fin    = (float2*)(ws + OFF_FIN);
  u32* cnt   = (u32*)(ws + OFF_CNT);
  u32* rowp  = (u32*)(ws + OFF_ROWP);
  u32* cur   = (u32*)(ws + OFF_CUR);
  u32* edges = (u32*)(ws + OFF_EDG);
  u32* bsum  = (u32*)(ws + OFF_BS);

  // ---- CSR segmented by (relation, dst) — shared by both layers ----
  k_zero<<<(NT + 255) / 256, 256, 0, stream>>>(cnt, cur);
  k_hist<<<1024, 256, 0, stream>>>(dstArr, etyp, cnt);
  k_scan1<<<SCANB, 512, 0, stream>>>(cnt, rowp, bsum);
  k_scan2<<<1, 1024, 0, stream>>>(bsum, rowp);
  k_scan3<<<SCANB, 512, 0, stream>>>(rowp, bsum);
  k_scatter<<<1024, 256, 0, stream>>>(srcArr, dstArr, etyp, rowp, cur, edges);
  k_repack<<<(2 * 17 * 4096 + 255) / 256, 256, 0, stream>>>(WQ, WK, WV, Wcat, Wself, pw);

  for (int l = 0; l < 2; l++){
    const float* xcur = (l == 0) ? x0 : out;
    const float* pwL = pw + (size_t)l * 17 * 4096;
    // Q for all 4 relations (mats 0-3), bf16
    k_gemm64<__hip_bfloat16><<<dim3(1563, 4), 256, 0, stream>>>(xcur, 0L, pwL, QbW, (long)NN * 64);
    for (int r = 0; r < 4; r++){
      k_gemmKV<<<1563, 256, 0, stream>>>(xcur, pwL + (4 + r) * 4096, pwL + (8 + r) * 4096, kvp);
      k_gather<<<NN / 4, 256, 0, stream>>>(edges, rowp + (size_t)r * NN, kvp,
                                           Qb + (size_t)r * NN * 64,
                                           Sb + (size_t)r * NN * 64,
                                           alphaB + (size_t)r * NN * 8);
    }
    k_stats1<<<dim3(32, 32), 256, 0, stream>>>(alphaB, part);
    k_stats2<<<1, 64, 0, stream>>>(part, fin);
    k_msggemm<<<dim3(1563, 4), 256, 0, stream>>>(Sb, alphaB, fin, pwL + 13 * 4096, stackedB);
    k_final<<<NN / 4, 256, 0, stream>>>(stackedB, xcur, pwL + 12 * 4096,
                                        semw + l * 64, semb + l, lng + l * 64, lnb + l * 64, out);
  }
  (void)in_sizes; (void)n_in; (void)out_size; (void)ws_size;
}

// Round 3
// 1007.462 us; speedup vs baseline: 1.2142x; 1.2142x over previous
//
#include <hip/hip_runtime.h>
#include <hip/hip_bf16.h>

#define NN 100000
#define EE 1600000
#define RRR 4
#define HHH 8
#define NT 400000      // RRR * NN
#define SCANB 782      // ceil(NT / 512)

typedef unsigned int u32;
typedef unsigned short u16;

// ---------------- workspace layout (bytes), total ~152.6 MB ----------------
static constexpr size_t OFF_KV   = 0;              // u32 [N][64] packed KV per relation; later bf16 self [N][64]
static constexpr size_t OFF_Q    = 25600000;       // bf16 [4][N][64] Q; ALIASED by 'stacked' after gathers
static constexpr size_t OFF_S    = 76800000;       // bf16 [4][N][64] V-sums
static constexpr size_t OFF_AL   = 128000000;      // f32  [4][N][8] energy sums
static constexpr size_t OFF_PW   = 140800000;      // f32  [2][17][4096] packed weights
static constexpr size_t OFF_PART = 141357056;      // float2 [32][32] softmax partials
static constexpr size_t OFF_FIN  = 141365248;      // float2 [32]
static constexpr size_t OFF_CNT  = 141365504;      // u32 [NT]
static constexpr size_t OFF_ROWP = 142965504;      // u32 [NT+1] (+pad)
static constexpr size_t OFF_CUR  = 144565520;      // u32 [NT]
static constexpr size_t OFF_EDG  = 146165520;      // u32 [E] src only (relation implicit in segment)
static constexpr size_t OFF_BS   = 152565520;      // u32 [SCANB]

__device__ inline u16 f2bf(float f){
  union { __hip_bfloat16 h; u16 u; } cv; cv.h = __float2bfloat16(f); return cv.u;
}
__device__ inline float bf2f(u16 u){ return __uint_as_float(((u32)u) << 16); }

__device__ inline void store4(float* p, float a, float b, float c, float d){
  float4 v; v.x = a; v.y = b; v.z = c; v.w = d; *(float4*)p = v;
}
__device__ inline void store4(__hip_bfloat16* p, float a, float b, float c, float d){
  ushort4 v; v.x = f2bf(a); v.y = f2bf(b); v.z = f2bf(c); v.w = f2bf(d); *(ushort4*)p = v;
}

// ---------------- zero fill ----------------
__global__ __launch_bounds__(256) void k_zero(u32* __restrict__ a, u32* __restrict__ b){
  int i = blockIdx.x * 256 + threadIdx.x;
  if (i < NT){ a[i] = 0u; b[i] = 0u; }
}

// ---------------- CSR build, segmented by (relation, dst) ----------------
__global__ __launch_bounds__(256) void k_hist(const int* __restrict__ dst, const int* __restrict__ typ,
                                              u32* __restrict__ cnt){
  for (int e = blockIdx.x * blockDim.x + threadIdx.x; e < EE; e += gridDim.x * blockDim.x)
    atomicAdd(&cnt[typ[e] * NN + dst[e]], 1u);
}

__global__ __launch_bounds__(512) void k_scan1(const u32* __restrict__ cnt, u32* __restrict__ rowp,
                                               u32* __restrict__ bsum){
  __shared__ u32 tmp[512];
  int t = threadIdx.x;
  int i = blockIdx.x * 512 + t;
  u32 v = (i < NT) ? cnt[i] : 0u;
  tmp[t] = v; __syncthreads();
  for (int off = 1; off < 512; off <<= 1){
    u32 add = (t >= off) ? tmp[t - off] : 0u; __syncthreads();
    tmp[t] += add; __syncthreads();
  }
  if (i < NT) rowp[i] = tmp[t] - v;
  if (t == 511) bsum[blockIdx.x] = tmp[t];
}

__global__ __launch_bounds__(1024) void k_scan2(u32* __restrict__ bsum, u32* __restrict__ rowp){
  __shared__ u32 tmp[1024];
  int t = threadIdx.x;
  u32 v = (t < SCANB) ? bsum[t] : 0u;
  tmp[t] = v; __syncthreads();
  for (int off = 1; off < 1024; off <<= 1){
    u32 add = (t >= off) ? tmp[t - off] : 0u; __syncthreads();
    tmp[t] += add; __syncthreads();
  }
  if (t < SCANB) bsum[t] = tmp[t] - v;
  if (t == 0) rowp[NT] = EE;
}

__global__ __launch_bounds__(512) void k_scan3(u32* __restrict__ rowp, const u32* __restrict__ bsum){
  int i = blockIdx.x * 512 + threadIdx.x;
  if (i < NT) rowp[i] += bsum[blockIdx.x];
}

__global__ __launch_bounds__(256) void k_scatter(const int* __restrict__ src, const int* __restrict__ dst,
                                                 const int* __restrict__ typ, const u32* __restrict__ rowp,
                                                 u32* __restrict__ cur, u32* __restrict__ edges){
  for (int e = blockIdx.x * blockDim.x + threadIdx.x; e < EE; e += gridDim.x * blockDim.x){
    int seg = typ[e] * NN + dst[e];
    u32 pos = rowp[seg] + atomicAdd(&cur[seg], 1u);
    edges[pos] = (u32)src[e];
  }
}

// ---------------- weight repack (both layers): pw[l][mat][c][hd] ----------------
__global__ __launch_bounds__(256) void k_repack(const float* __restrict__ WQ, const float* __restrict__ WK,
                                                const float* __restrict__ WV, const float* __restrict__ Wcat,
                                                const float* __restrict__ Wself, float* __restrict__ pw){
  int t = blockIdx.x * 256 + threadIdx.x;
  if (t >= 2 * 17 * 4096) return;
  int l = t / (17 * 4096), rem = t % (17 * 4096);
  int mat = rem >> 12, idx = rem & 4095;
  int c = idx >> 6, hd = idx & 63;
  float v;
  if (mat < 12){
    int kind = mat >> 2, r = mat & 3;
    int h = hd >> 3, d = hd & 7;
    const float* Wsrc = (kind == 0) ? WQ : (kind == 1) ? WK : WV;
    v = Wsrc[((((l * RRR + r) * HHH + h) * 64) + c) * 8 + d];
  } else if (mat == 12){
    v = Wself[(l * 64 + c) * 64 + hd];
  } else {
    int r = mat - 13;
    v = Wcat[(((l * RRR + r) * 64) + c) * 64 + hd];
  }
  pw[t] = v;
}

// ---------------- generic N x 64 @ 64 x 64 GEMM (mat = blockIdx.y) ----------------
template<typename OutT>
__global__ __launch_bounds__(256) void k_gemm64(const float* __restrict__ Abase, long strideA,
                                                const float* __restrict__ Wp,
                                                OutT* __restrict__ Obase, long strideO){
  __shared__ float At[64][64];
  __shared__ float Wl[64][64];
  int mat = blockIdx.y;
  const float* A = Abase + (long)mat * strideA;
  const float* W = Wp + mat * 4096;
  OutT* O = Obase + (long)mat * strideO;
  int t = threadIdx.x;
  int n0 = blockIdx.x * 64;
  {
    const float4* w4 = (const float4*)W;
    float4* l4 = (float4*)(&Wl[0][0]);
    #pragma unroll
    for (int i = 0; i < 4; i++) l4[t + 256 * i] = w4[t + 256 * i];
  }
  {
    int nl = t & 63, cq = (t >> 6) * 16;
    int n = n0 + nl;
    #pragma unroll
    for (int j = 0; j < 4; j++){
      float4 v; v.x = v.y = v.z = v.w = 0.f;
      if (n < NN) v = *(const float4*)(A + (long)n * 64 + cq + j * 4);
      At[cq + j * 4 + 0][nl] = v.x; At[cq + j * 4 + 1][nl] = v.y;
      At[cq + j * 4 + 2][nl] = v.z; At[cq + j * 4 + 3][nl] = v.w;
    }
  }
  __syncthreads();
  int nl4 = (t & 15) * 4;
  int h4  = (t >> 4) * 4;
  float acc[4][4] = {};
  #pragma unroll 4
  for (int c = 0; c < 64; c++){
    float4 av = *(const float4*)(&At[c][nl4]);
    float4 wv = *(const float4*)(&Wl[c][h4]);
    acc[0][0] += av.x * wv.x; acc[0][1] += av.x * wv.y; acc[0][2] += av.x * wv.z; acc[0][3] += av.x * wv.w;
    acc[1][0] += av.y * wv.x; acc[1][1] += av.y * wv.y; acc[1][2] += av.y * wv.z; acc[1][3] += av.y * wv.w;
    acc[2][0] += av.z * wv.x; acc[2][1] += av.z * wv.y; acc[2][2] += av.z * wv.z; acc[2][3] += av.z * wv.w;
    acc[3][0] += av.w * wv.x; acc[3][1] += av.w * wv.y; acc[3][2] += av.w * wv.z; acc[3][3] += av.w * wv.w;
  }
  #pragma unroll
  for (int i = 0; i < 4; i++){
    int n = n0 + nl4 + i;
    if (n < NN) store4(&O[(long)n * 64 + h4], acc[i][0], acc[i][1], acc[i][2], acc[i][3]);
  }
}

// ---------------- K,V GEMM for one relation, packed u32 output ----------------
__global__ __launch_bounds__(256) void k_gemmKV(const float* __restrict__ A,
                                                const float* __restrict__ pwK, const float* __restrict__ pwV,
                                                u32* __restrict__ kvp){
  __shared__ float At[64][64];
  __shared__ float Wk[64][64];
  __shared__ float Wv[64][64];
  int t = threadIdx.x;
  int n0 = blockIdx.x * 64;
  {
    const float4* wk4 = (const float4*)pwK;
    const float4* wv4 = (const float4*)pwV;
    float4* lk = (float4*)(&Wk[0][0]);
    float4* lv = (float4*)(&Wv[0][0]);
    #pragma unroll
    for (int i = 0; i < 4; i++){ lk[t + 256 * i] = wk4[t + 256 * i]; lv[t + 256 * i] = wv4[t + 256 * i]; }
  }
  {
    int nl = t & 63, cq = (t >> 6) * 16;
    int n = n0 + nl;
    #pragma unroll
    for (int j = 0; j < 4; j++){
      float4 v; v.x = v.y = v.z = v.w = 0.f;
      if (n < NN) v = *(const float4*)(A + (long)n * 64 + cq + j * 4);
      At[cq + j * 4 + 0][nl] = v.x; At[cq + j * 4 + 1][nl] = v.y;
      At[cq + j * 4 + 2][nl] = v.z; At[cq + j * 4 + 3][nl] = v.w;
    }
  }
  __syncthreads();
  int nl4 = (t & 15) * 4;
  int h4  = (t >> 4) * 4;
  float aK[4][4] = {}, aV[4][4] = {};
  #pragma unroll 4
  for (int c = 0; c < 64; c++){
    float4 av = *(const float4*)(&At[c][nl4]);
    float4 wk = *(const float4*)(&Wk[c][h4]);
    float4 wv = *(const float4*)(&Wv[c][h4]);
    aK[0][0] += av.x * wk.x; aK[0][1] += av.x * wk.y; aK[0][2] += av.x * wk.z; aK[0][3] += av.x * wk.w;
    aK[1][0] += av.y * wk.x; aK[1][1] += av.y * wk.y; aK[1][2] += av.y * wk.z; aK[1][3] += av.y * wk.w;
    aK[2][0] += av.z * wk.x; aK[2][1] += av.z * wk.y; aK[2][2] += av.z * wk.z; aK[2][3] += av.z * wk.w;
    aK[3][0] += av.w * wk.x; aK[3][1] += av.w * wk.y; aK[3][2] += av.w * wk.z; aK[3][3] += av.w * wk.w;
    aV[0][0] += av.x * wv.x; aV[0][1] += av.x * wv.y; aV[0][2] += av.x * wv.z; aV[0][3] += av.x * wv.w;
    aV[1][0] += av.y * wv.x; aV[1][1] += av.y * wv.y; aV[1][2] += av.y * wv.z; aV[1][3] += av.y * wv.w;
    aV[2][0] += av.z * wv.x; aV[2][1] += av.z * wv.y; aV[2][2] += av.z * wv.z; aV[2][3] += av.z * wv.w;
    aV[3][0] += av.w * wv.x; aV[3][1] += av.w * wv.y; aV[3][2] += av.w * wv.z; aV[3][3] += av.w * wv.w;
  }
  #pragma unroll
  for (int i = 0; i < 4; i++){
    int n = n0 + nl4 + i;
    if (n < NN){
      uint4 pk;
      pk.x = (u32)f2bf(aK[i][0]) | ((u32)f2bf(aV[i][0]) << 16);
      pk.y = (u32)f2bf(aK[i][1]) | ((u32)f2bf(aV[i][1]) << 16);
      pk.z = (u32)f2bf(aK[i][2]) | ((u32)f2bf(aV[i][2]) << 16);
      pk.w = (u32)f2bf(aK[i][3]) | ((u32)f2bf(aV[i][3]) << 16);
      *(uint4*)(&kvp[(long)n * 64 + h4]) = pk;
    }
  }
}

// ---------------- edge gather: lane-parallel adjacency load + 4-deep unroll ----------------
__global__ __launch_bounds__(256) void k_gather(const u32* __restrict__ edges, const u32* __restrict__ rowpR,
                                                const u32* __restrict__ kvp, const u16* __restrict__ Qr,
                                                u16* __restrict__ Sr, float* __restrict__ alphaR){
  int wid = threadIdx.x >> 6, lane = threadIdx.x & 63;
  int n = blockIdx.x * 4 + wid;
  float q = bf2f(Qr[(long)n * 64 + lane]);
  u32 beg = rowpR[n], end = rowpR[n + 1];
  float sa = 0.f, aa = 0.f;
  const float inv_sqrt_d = 0.35355339059327373f;   // 1/sqrt(8)
  for (u32 base = beg; base < end; base += 64){
    u32 cnt = (end - base < 64u) ? (end - base) : 64u;
    u32 eidx = (base + (u32)lane < end) ? edges[base + lane] : 0u;   // whole adjacency chunk in 1 load
    u32 j = 0;
    for (; j + 4 <= cnt; j += 4){
      int s0 = __shfl((int)eidx, (int)j);
      int s1 = __shfl((int)eidx, (int)j + 1);
      int s2 = __shfl((int)eidx, (int)j + 2);
      int s3 = __shfl((int)eidx, (int)j + 3);
      u32 w0 = kvp[(long)s0 * 64 + lane];
      u32 w1 = kvp[(long)s1 * 64 + lane];
      u32 w2 = kvp[(long)s2 * 64 + lane];
      u32 w3 = kvp[(long)s3 * 64 + lane];
      float p0 = q * bf2f((u16)(w0 & 0xFFFFu));
      float p1 = q * bf2f((u16)(w1 & 0xFFFFu));
      float p2 = q * bf2f((u16)(w2 & 0xFFFFu));
      float p3 = q * bf2f((u16)(w3 & 0xFFFFu));
      p0 += __shfl_xor(p0, 1); p1 += __shfl_xor(p1, 1); p2 += __shfl_xor(p2, 1); p3 += __shfl_xor(p3, 1);
      p0 += __shfl_xor(p0, 2); p1 += __shfl_xor(p1, 2); p2 += __shfl_xor(p2, 2); p3 += __shfl_xor(p3, 2);
      p0 += __shfl_xor(p0, 4); p1 += __shfl_xor(p1, 4); p2 += __shfl_xor(p2, 4); p3 += __shfl_xor(p3, 4);
      float e0 = p0 * inv_sqrt_d; e0 = (e0 > 0.f) ? e0 : 0.01f * e0;
      float e1 = p1 * inv_sqrt_d; e1 = (e1 > 0.f) ? e1 : 0.01f * e1;
      float e2 = p2 * inv_sqrt_d; e2 = (e2 > 0.f) ? e2 : 0.01f * e2;
      float e3 = p3 * inv_sqrt_d; e3 = (e3 > 0.f) ? e3 : 0.01f * e3;
      aa += (e0 + e1) + (e2 + e3);
      sa += (bf2f((u16)(w0 >> 16)) + bf2f((u16)(w1 >> 16))) +
            (bf2f((u16)(w2 >> 16)) + bf2f((u16)(w3 >> 16)));
    }
    for (; j < cnt; ++j){
      int s = __shfl((int)eidx, (int)j);
      u32 w = kvp[(long)s * 64 + lane];
      float p = q * bf2f((u16)(w & 0xFFFFu));
      p += __shfl_xor(p, 1);
      p += __shfl_xor(p, 2);
      p += __shfl_xor(p, 4);
      float e = p * inv_sqrt_d;
      e = (e > 0.f) ? e : 0.01f * e;
      aa += e;
      sa += bf2f((u16)(w >> 16));
    }
  }
  Sr[(long)n * 64 + lane] = f2bf(sa);
  if ((lane & 7) == 0) alphaR[(long)n * 8 + (lane >> 3)] = aa;
}

// ---------------- column softmax stats over N per (r,h) ----------------
__global__ __launch_bounds__(256) void k_stats1(const float* __restrict__ alpha, float2* __restrict__ part){
  int col = blockIdx.x;            // r*8+h
  int r = col >> 3, h = col & 7;
  int chunk = blockIdx.y;
  const int per = (NN + 31) / 32;
  int nbeg = chunk * per;
  int nend = nbeg + per; if (nend > NN) nend = NN;
  int t = threadIdx.x;
  float m = -1e30f, s = 0.f;
  for (int n = nbeg + t; n < nend; n += 256){
    float a = alpha[((long)r * NN + n) * 8 + h];
    if (a > m){ s *= expf(m - a); m = a; }
    s += expf(a - m);
  }
  __shared__ float sm[256], ss[256];
  sm[t] = m; ss[t] = s; __syncthreads();
  for (int off = 128; off > 0; off >>= 1){
    if (t < off){
      float m2 = sm[t + off], s2 = ss[t + off];
      float M = fmaxf(sm[t], m2);
      ss[t] = ss[t] * expf(sm[t] - M) + s2 * expf(m2 - M);
      sm[t] = M;
    }
    __syncthreads();
  }
  if (t == 0) part[col * 32 + chunk] = make_float2(sm[0], ss[0]);
}

__global__ void k_stats2(const float2* __restrict__ part, float2* __restrict__ fin){
  int col = threadIdx.x;
  if (col < 32){
    float M = -1e30f, S = 0.f;
    for (int i = 0; i < 32; i++){
      float2 p = part[col * 32 + i];
      float Mn = fmaxf(M, p.x);
      S = S * expf(M - Mn) + p.y * expf(p.x - Mn);
      M = Mn;
    }
    fin[col] = make_float2(M, 1.f / S);
  }
}

// ---------------- message GEMM with fused alpha apply ----------------
__global__ __launch_bounds__(256) void k_msggemm(const u16* __restrict__ S, const float* __restrict__ alpha,
                                                 const float2* __restrict__ fin, const float* __restrict__ pwCat,
                                                 u16* __restrict__ stacked){
  __shared__ float At[64][64];
  __shared__ float Wl[64][64];
  int r = blockIdx.y;
  int t = threadIdx.x;
  int n0 = blockIdx.x * 64;
  {
    const float4* w4 = (const float4*)(pwCat + r * 4096);
    float4* l4 = (float4*)(&Wl[0][0]);
    #pragma unroll
    for (int i = 0; i < 4; i++) l4[t + 256 * i] = w4[t + 256 * i];
  }
  {
    int nl = t & 63, cq = (t >> 6) * 16;
    int n = n0 + nl;
    int na = (n < NN) ? n : (NN - 1);
    int h0 = cq >> 3;
    float2 f0 = fin[r * 8 + h0];
    float2 f1 = fin[r * 8 + h0 + 1];
    float a0 = alpha[((long)r * NN + na) * 8 + h0];
    float a1 = alpha[((long)r * NN + na) * 8 + h0 + 1];
    float w0 = expf(a0 - f0.x) * f0.y;
    float w1 = expf(a1 - f1.x) * f1.y;
    const u32* sp = (const u32*)(S + ((long)r * NN + na) * 64 + cq);
    #pragma unroll
    for (int jj = 0; jj < 8; jj++){
      u32 b = sp[jj];
      float wm = (jj < 4) ? w0 : w1;
      At[cq + jj * 2 + 0][nl] = bf2f((u16)(b & 0xFFFFu)) * wm;
      At[cq + jj * 2 + 1][nl] = bf2f((u16)(b >> 16)) * wm;
    }
  }
  __syncthreads();
  int nl4 = (t & 15) * 4;
  int h4  = (t >> 4) * 4;
  float acc[4][4] = {};
  #pragma unroll 4
  for (int c = 0; c < 64; c++){
    float4 av = *(const float4*)(&At[c][nl4]);
    float4 wv = *(const float4*)(&Wl[c][h4]);
    acc[0][0] += av.x * wv.x; acc[0][1] += av.x * wv.y; acc[0][2] += av.x * wv.z; acc[0][3] += av.x * wv.w;
    acc[1][0] += av.y * wv.x; acc[1][1] += av.y * wv.y; acc[1][2] += av.y * wv.z; acc[1][3] += av.y * wv.w;
    acc[2][0] += av.z * wv.x; acc[2][1] += av.z * wv.y; acc[2][2] += av.z * wv.z; acc[2][3] += av.z * wv.w;
    acc[3][0] += av.w * wv.x; acc[3][1] += av.w * wv.y; acc[3][2] += av.w * wv.z; acc[3][3] += av.w * wv.w;
  }
  #pragma unroll
  for (int i = 0; i < 4; i++){
    int n = n0 + nl4 + i;
    if (n < NN){
      ushort4 v;
      v.x = f2bf(acc[i][0]); v.y = f2bf(acc[i][1]); v.z = f2bf(acc[i][2]); v.w = f2bf(acc[i][3]);
      *(ushort4*)(&stacked[((long)r * NN + n) * 64 + h4]) = v;
    }
  }
}

// ---------------- semantic attn + gelu + residual + LN (pure streaming + shfl) ----------------
__global__ __launch_bounds__(256) void k_final(const u16* __restrict__ stacked, const u16* __restrict__ selfb,
                                               const float* __restrict__ xin,
                                               const float* __restrict__ semw, const float* __restrict__ semb,
                                               const float* __restrict__ lng, const float* __restrict__ lnb,
                                               float* __restrict__ xout){
  int t = threadIdx.x;
  int wid = t >> 6, lane = t & 63;
  int n = blockIdx.x * 4 + wid;
  float st[4];
  #pragma unroll
  for (int r = 0; r < 4; r++) st[r] = bf2f(stacked[((long)r * NN + n) * 64 + lane]);
  float sw = semw[lane];
  float lg[4];
  #pragma unroll
  for (int r = 0; r < 4; r++){
    float p = st[r] * sw;
    #pragma unroll
    for (int o = 1; o < 64; o <<= 1) p += __shfl_xor(p, o);
    lg[r] = p + semb[0];
  }
  float mx = fmaxf(fmaxf(lg[0], lg[1]), fmaxf(lg[2], lg[3]));
  float e0 = expf(lg[0] - mx), e1 = expf(lg[1] - mx), e2 = expf(lg[2] - mx), e3 = expf(lg[3] - mx);
  float inv = 1.f / (e0 + e1 + e2 + e3);
  float agg = (e0 * st[0] + e1 * st[1] + e2 * st[2] + e3 * st[3]) * inv;
  float pre = bf2f(selfb[(long)n * 64 + lane]) + agg;
  float ge = 0.5f * pre * (1.f + erff(pre * 0.70710678118654752f));
  float y = xin[(long)n * 64 + lane] + ge;
  float mu = y;
  #pragma unroll
  for (int o = 1; o < 64; o <<= 1) mu += __shfl_xor(mu, o);
  mu *= (1.f / 64.f);
  float d = y - mu;
  float vv = d * d;
  #pragma unroll
  for (int o = 1; o < 64; o <<= 1) vv += __shfl_xor(vv, o);
  vv *= (1.f / 64.f);
  xout[(long)n * 64 + lane] = d * rsqrtf(vv + 1e-5f) * lng[lane] + lnb[lane];
}

extern "C" void kernel_launch(void* const* d_in, const int* in_sizes, int n_in,
                              void* d_out, int out_size, void* d_ws, size_t ws_size,
                              hipStream_t stream){
  const float* x0    = (const float*)d_in[0];
  const int*   eidx  = (const int*)d_in[1];
  const int*   etyp  = (const int*)d_in[2];
  const float* WQ    = (const float*)d_in[3];
  const float* WK    = (const float*)d_in[4];
  const float* WV    = (const float*)d_in[5];
  const float* Wcat  = (const float*)d_in[6];
  const float* semw  = (const float*)d_in[7];
  const float* semb  = (const float*)d_in[8];
  const float* Wself = (const float*)d_in[9];
  const float* lng   = (const float*)d_in[10];
  const float* lnb   = (const float*)d_in[11];
  float* out = (float*)d_out;
  char* ws = (char*)d_ws;

  const int* srcArr = eidx;        // edge_index row 0 = src (j)
  const int* dstArr = eidx + EE;   // row 1 = dst (i)

  u32*  kvp      = (u32*)(ws + OFF_KV);
  __hip_bfloat16* QbW = (__hip_bfloat16*)(ws + OFF_Q);
  u16*  Qb       = (u16*)(ws + OFF_Q);
  u16*  stackedB = (u16*)(ws + OFF_Q);     // aliases dead Q after gathers
  __hip_bfloat16* selfbW = (__hip_bfloat16*)(ws + OFF_KV);   // aliases dead kvp after gathers
  u16*  selfb    = (u16*)(ws + OFF_KV);
  u16*  Sb       = (u16*)(ws + OFF_S);
  float* alphaB  = (float*)(ws + OFF_AL);
  float* pw      = (float*)(ws + OFF_PW);
  float2* part   = (float2*)(ws + OFF_PART);
  float2* fin    = (float2*)(ws + OFF_FIN);
  u32* cnt   = (u32*)(ws + OFF_CNT);
  u32* rowp  = (u32*)(ws + OFF_ROWP);
  u32* cur   = (u32*)(ws + OFF_CUR);
  u32* edges = (u32*)(ws + OFF_EDG);
  u32* bsum  = (u32*)(ws + OFF_BS);

  // ---- CSR segmented by (relation, dst) — shared by both layers ----
  k_zero<<<(NT + 255) / 256, 256, 0, stream>>>(cnt, cur);
  k_hist<<<1024, 256, 0, stream>>>(dstArr, etyp, cnt);
  k_scan1<<<SCANB, 512, 0, stream>>>(cnt, rowp, bsum);
  k_scan2<<<1, 1024, 0, stream>>>(bsum, rowp);
  k_scan3<<<SCANB, 512, 0, stream>>>(rowp, bsum);
  k_scatter<<<1024, 256, 0, stream>>>(srcArr, dstArr, etyp, rowp, cur, edges);
  k_repack<<<(2 * 17 * 4096 + 255) / 256, 256, 0, stream>>>(WQ, WK, WV, Wcat, Wself, pw);

  for (int l = 0; l < 2; l++){
    const float* xcur = (l == 0) ? x0 : out;
    const float* pwL = pw + (size_t)l * 17 * 4096;
    // Q for all 4 relations (mats 0-3), bf16
    k_gemm64<__hip_bfloat16><<<dim3(1563, 4), 256, 0, stream>>>(xcur, 0L, pwL, QbW, (long)NN * 64);
    for (int r = 0; r < 4; r++){
      k_gemmKV<<<1563, 256, 0, stream>>>(xcur, pwL + (4 + r) * 4096, pwL + (8 + r) * 4096, kvp);
      k_gather<<<NN / 4, 256, 0, stream>>>(edges, rowp + (size_t)r * NN, kvp,
                                           Qb + (size_t)r * NN * 64,
                                           Sb + (size_t)r * NN * 64,
                                           alphaB + (size_t)r * NN * 8);
    }
    // self = x @ Wself (bf16) into the now-dead kvp region
    k_gemm64<__hip_bfloat16><<<dim3(1563, 1), 256, 0, stream>>>(xcur, 0L, pwL + 12 * 4096, selfbW, 0L);
    k_stats1<<<dim3(32, 32), 256, 0, stream>>>(alphaB, part);
    k_stats2<<<1, 64, 0, stream>>>(part, fin);
    k_msggemm<<<dim3(1563, 4), 256, 0, stream>>>(Sb, alphaB, fin, pwL + 13 * 4096, stackedB);
    k_final<<<NN / 4, 256, 0, stream>>>(stackedB, selfb, xcur,
                                        semw + l * 64, semb + l, lng + l * 64, lnb + l * 64, out);
  }
  (void)in_sizes; (void)n_in; (void)out_size; (void)ws_size;
}

// Round 4
// 887.375 us; speedup vs baseline: 1.3785x; 1.1353x over previous
//
#include <hip/hip_runtime.h>
#include <hip/hip_bf16.h>

#define NN 100000
#define EE 1600000
#define RRR 4
#define HHH 8
#define NT 400000      // RRR * NN
#define NBUCK 1563     // ceil(NT / 256)
#define BCAP 2048

typedef unsigned int u32;
typedef unsigned short u16;
typedef unsigned long long u64;
typedef __attribute__((ext_vector_type(8))) short bf16x8;
typedef __attribute__((ext_vector_type(4))) float f32x4;

// ---------------- workspace layout (bytes), total ~149.1 MB ----------------
static constexpr size_t OFF_KV   = 0;              // u32 [N][64] packed KV (per-relation reuse); bf16 self aliases later
static constexpr size_t OFF_Q    = 25600000;       // bf16 [4][N][64] Q; 'stacked' aliases after gathers
static constexpr size_t OFF_S    = 76800000;       // bf16 [4][N][64] V-sums; bstore u64[NBUCK*BCAP] aliases during CSR build
static constexpr size_t OFF_AL   = 128000000;      // f32  [4][N][8] energy sums
static constexpr size_t OFF_PW   = 140800000;      // u16  [2][17][64][64] bf16 weights, [out][c] layout
static constexpr size_t OFF_PART = 141100000;      // float2 [32][32]
static constexpr size_t OFF_FIN  = 141110000;      // float2 [32]
static constexpr size_t OFF_BCNT = 141111008;      // u32 [NBUCK]
static constexpr size_t OFF_BST  = 141118000;      // u32 [NBUCK]
static constexpr size_t OFF_ROWP = 141125000;      // u32 [NT+1]
static constexpr size_t OFF_EDG  = 142726000;      // u32 [E]

__device__ inline u16 f2bf(float f){
  union { __hip_bfloat16 h; u16 u; } cv; cv.h = __float2bfloat16(f); return cv.u;
}
__device__ inline float bf2f(u16 u){ return __uint_as_float(((u32)u) << 16); }

// ---------------- CSR build: bucket append + per-bucket LDS counting sort ----------------
__global__ __launch_bounds__(256) void k_binit(u32* __restrict__ bcnt){
  int i = blockIdx.x * 256 + threadIdx.x;
  if (i < NBUCK) bcnt[i] = 0u;
}

__global__ __launch_bounds__(256) void k_bucket(const int* __restrict__ src, const int* __restrict__ dst,
                                                const int* __restrict__ typ, u32* __restrict__ bcnt,
                                                u64* __restrict__ bstore){
  for (int e = blockIdx.x * blockDim.x + threadIdx.x; e < EE; e += gridDim.x * blockDim.x){
    int seg = typ[e] * NN + dst[e];
    int b = seg >> 8;
    u32 pos = atomicAdd(&bcnt[b], 1u);
    if (pos < BCAP) bstore[(size_t)b * BCAP + pos] = ((u64)(u32)seg << 32) | (u32)src[e];
  }
}

__global__ __launch_bounds__(1024) void k_bscan(const u32* __restrict__ bcnt, u32* __restrict__ bstart,
                                                u32* __restrict__ rowp){
  __shared__ u32 tmp[1024];
  int t = threadIdx.x;
  int i0 = 2 * t, i1 = 2 * t + 1;
  u32 a = (i0 < NBUCK) ? min(bcnt[i0], (u32)BCAP) : 0u;
  u32 b = (i1 < NBUCK) ? min(bcnt[i1], (u32)BCAP) : 0u;
  u32 s = a + b;
  tmp[t] = s; __syncthreads();
  for (int off = 1; off < 1024; off <<= 1){
    u32 add = (t >= off) ? tmp[t - off] : 0u; __syncthreads();
    tmp[t] += add; __syncthreads();
  }
  u32 excl = tmp[t] - s;
  if (i0 < NBUCK) bstart[i0] = excl;
  if (i1 < NBUCK) bstart[i1] = excl + a;
  if (t == 0) rowp[NT] = EE;
}

__global__ __launch_bounds__(256) void k_bsort(const u64* __restrict__ bstore, const u32* __restrict__ bcnt,
                                               const u32* __restrict__ bstart, u32* __restrict__ rowp,
                                               u32* __restrict__ edges){
  __shared__ u16 skey[BCAP];
  __shared__ u32 ssrc[BCAP];
  __shared__ u32 off[256], cur[256], sc[256];
  int b = blockIdx.x, t = threadIdx.x;
  u32 cnt = min(bcnt[b], (u32)BCAP);
  u32 base = bstart[b];
  for (u32 i = t; i < cnt; i += 256){
    u64 v = bstore[(size_t)b * BCAP + i];
    skey[i] = (u16)((v >> 32) & 255u);
    ssrc[i] = (u32)v;
  }
  off[t] = 0u;
  __syncthreads();
  for (u32 i = t; i < cnt; i += 256) atomicAdd(&off[skey[i]], 1u);
  __syncthreads();
  u32 c0 = off[t];
  sc[t] = c0; __syncthreads();
  for (int o = 1; o < 256; o <<= 1){
    u32 add = (t >= o) ? sc[t - o] : 0u; __syncthreads();
    sc[t] += add; __syncthreads();
  }
  u32 excl = sc[t] - c0;
  cur[t] = excl;
  int seg = b * 256 + t;
  if (seg < NT) rowp[seg] = base + excl;
  __syncthreads();
  for (u32 i = t; i < cnt; i += 256){
    u32 p = atomicAdd(&cur[skey[i]], 1u);
    edges[base + p] = ssrc[i];
  }
}

// ---------------- weight repack (both layers): pwB[l][mat][out][c] bf16 ----------------
// mats 0-3 Q r0-3 ; 4-7 K ; 8-11 V ; 12 W_self ; 13-16 Wcat r0-3
__global__ __launch_bounds__(256) void k_repackbf(const float* __restrict__ WQ, const float* __restrict__ WK,
                                                  const float* __restrict__ WV, const float* __restrict__ Wcat,
                                                  const float* __restrict__ Wself, u16* __restrict__ pwB){
  int t = blockIdx.x * 256 + threadIdx.x;
  if (t >= 2 * 17 * 4096) return;
  int l = t / (17 * 4096), rem = t % (17 * 4096);
  int mat = rem >> 12, idx = rem & 4095;
  int out = idx >> 6, c = idx & 63;
  float v;
  if (mat < 12){
    int kind = mat >> 2, r = mat & 3;
    int h = out >> 3, d = out & 7;
    const float* Wsrc = (kind == 0) ? WQ : (kind == 1) ? WK : WV;
    v = Wsrc[((((l * RRR + r) * HHH + h) * 64) + c) * 8 + d];
  } else if (mat == 12){
    v = Wself[(l * 64 + c) * 64 + out];
  } else {
    int r = mat - 13;
    v = Wcat[(((l * RRR + r) * 64) + c) * 64 + out];
  }
  pwB[t] = f2bf(v);
}

// ---------------- MFMA helpers ----------------
// A-frag (16x32): row = lane&15, k = (lane>>4)*8 + j (8 consecutive)
// B-frag (32x16): col = lane&15, k = (lane>>4)*8 + j  -> read from [out][c] layout
// D (16x16): col = lane&15, row = (lane>>4)*4 + reg

// ---------------- Q,K,V MFMA GEMM for one relation ----------------
__global__ __launch_bounds__(256) void k_qkv(const float* __restrict__ x,
                                             const u16* __restrict__ pwQ, const u16* __restrict__ pwK,
                                             const u16* __restrict__ pwV,
                                             u16* __restrict__ Qr, u32* __restrict__ kvp){
  __shared__ u16 xa[64][72];
  __shared__ u16 wt[3][64][72];
  int t = threadIdx.x;
  int n0 = blockIdx.x * 64;
  { // stage x -> bf16
    int row = t >> 2, c0 = (t & 3) * 16;
    int n = n0 + row;
    float4 v0 = {}, v1 = {}, v2 = {}, v3 = {};
    if (n < NN){
      const float4* xp = (const float4*)(x + (size_t)n * 64 + c0);
      v0 = xp[0]; v1 = xp[1]; v2 = xp[2]; v3 = xp[3];
    }
    ushort4* dp = (ushort4*)&xa[row][c0];
    dp[0] = make_ushort4(f2bf(v0.x), f2bf(v0.y), f2bf(v0.z), f2bf(v0.w));
    dp[1] = make_ushort4(f2bf(v1.x), f2bf(v1.y), f2bf(v1.z), f2bf(v1.w));
    dp[2] = make_ushort4(f2bf(v2.x), f2bf(v2.y), f2bf(v2.z), f2bf(v2.w));
    dp[3] = make_ushort4(f2bf(v3.x), f2bf(v3.y), f2bf(v3.z), f2bf(v3.w));
  }
  { // stage weights (already bf16, [out][c])
    const u32* p0 = (const u32*)pwQ;
    const u32* p1 = (const u32*)pwK;
    const u32* p2 = (const u32*)pwV;
    for (int idx = t; idx < 3 * 2048; idx += 256){
      int m = idx >> 11, rem = idx & 2047;
      int out = rem >> 5, cc = rem & 31;
      u32 w = (m == 0) ? p0[rem] : (m == 1) ? p1[rem] : p2[rem];
      *(u32*)&wt[m][out][cc * 2] = w;
    }
  }
  __syncthreads();
  int w = t >> 6, lane = t & 63;
  int ra = w * 16 + (lane & 15);
  int kg = (lane >> 4) * 8;
  int cb = lane & 15;
  int rb = (lane >> 4) * 4;
  bf16x8 a0 = *(const bf16x8*)&xa[ra][kg];
  bf16x8 a1 = *(const bf16x8*)&xa[ra][32 + kg];
  f32x4 z = {0.f, 0.f, 0.f, 0.f};
  { // Q
    f32x4 acc[4] = {z, z, z, z};
    #pragma unroll
    for (int t4 = 0; t4 < 4; t4++){
      bf16x8 b0 = *(const bf16x8*)&wt[0][t4 * 16 + cb][kg];
      bf16x8 b1 = *(const bf16x8*)&wt[0][t4 * 16 + cb][32 + kg];
      acc[t4] = __builtin_amdgcn_mfma_f32_16x16x32_bf16(a0, b0, acc[t4], 0, 0, 0);
      acc[t4] = __builtin_amdgcn_mfma_f32_16x16x32_bf16(a1, b1, acc[t4], 0, 0, 0);
    }
    #pragma unroll
    for (int t4 = 0; t4 < 4; t4++){
      #pragma unroll
      for (int i = 0; i < 4; i++){
        int n = n0 + w * 16 + rb + i;
        if (n < NN) Qr[(size_t)n * 64 + t4 * 16 + cb] = f2bf(acc[t4][i]);
      }
    }
  }
  { // K,V packed
    f32x4 ak[4] = {z, z, z, z};
    f32x4 av[4] = {z, z, z, z};
    #pragma unroll
    for (int t4 = 0; t4 < 4; t4++){
      bf16x8 bk0 = *(const bf16x8*)&wt[1][t4 * 16 + cb][kg];
      bf16x8 bk1 = *(const bf16x8*)&wt[1][t4 * 16 + cb][32 + kg];
      bf16x8 bv0 = *(const bf16x8*)&wt[2][t4 * 16 + cb][kg];
      bf16x8 bv1 = *(const bf16x8*)&wt[2][t4 * 16 + cb][32 + kg];
      ak[t4] = __builtin_amdgcn_mfma_f32_16x16x32_bf16(a0, bk0, ak[t4], 0, 0, 0);
      ak[t4] = __builtin_amdgcn_mfma_f32_16x16x32_bf16(a1, bk1, ak[t4], 0, 0, 0);
      av[t4] = __builtin_amdgcn_mfma_f32_16x16x32_bf16(a0, bv0, av[t4], 0, 0, 0);
      av[t4] = __builtin_amdgcn_mfma_f32_16x16x32_bf16(a1, bv1, av[t4], 0, 0, 0);
    }
    #pragma unroll
    for (int t4 = 0; t4 < 4; t4++){
      #pragma unroll
      for (int i = 0; i < 4; i++){
        int n = n0 + w * 16 + rb + i;
        if (n < NN) kvp[(size_t)n * 64 + t4 * 16 + cb] = (u32)f2bf(ak[t4][i]) | ((u32)f2bf(av[t4][i]) << 16);
      }
    }
  }
}

// ---------------- self MFMA GEMM (1 mat, u16 out) ----------------
__global__ __launch_bounds__(256) void k_self(const float* __restrict__ x, const u16* __restrict__ pwS,
                                              u16* __restrict__ outb){
  __shared__ u16 xa[64][72];
  __shared__ u16 wt[64][72];
  int t = threadIdx.x;
  int n0 = blockIdx.x * 64;
  {
    int row = t >> 2, c0 = (t & 3) * 16;
    int n = n0 + row;
    float4 v0 = {}, v1 = {}, v2 = {}, v3 = {};
    if (n < NN){
      const float4* xp = (const float4*)(x + (size_t)n * 64 + c0);
      v0 = xp[0]; v1 = xp[1]; v2 = xp[2]; v3 = xp[3];
    }
    ushort4* dp = (ushort4*)&xa[row][c0];
    dp[0] = make_ushort4(f2bf(v0.x), f2bf(v0.y), f2bf(v0.z), f2bf(v0.w));
    dp[1] = make_ushort4(f2bf(v1.x), f2bf(v1.y), f2bf(v1.z), f2bf(v1.w));
    dp[2] = make_ushort4(f2bf(v2.x), f2bf(v2.y), f2bf(v2.z), f2bf(v2.w));
    dp[3] = make_ushort4(f2bf(v3.x), f2bf(v3.y), f2bf(v3.z), f2bf(v3.w));
  }
  {
    const u32* p0 = (const u32*)pwS;
    for (int idx = t; idx < 2048; idx += 256){
      int out = idx >> 5, cc = idx & 31;
      *(u32*)&wt[out][cc * 2] = p0[idx];
    }
  }
  __syncthreads();
  int w = t >> 6, lane = t & 63;
  int ra = w * 16 + (lane & 15);
  int kg = (lane >> 4) * 8;
  int cb = lane & 15;
  int rb = (lane >> 4) * 4;
  bf16x8 a0 = *(const bf16x8*)&xa[ra][kg];
  bf16x8 a1 = *(const bf16x8*)&xa[ra][32 + kg];
  f32x4 z = {0.f, 0.f, 0.f, 0.f};
  f32x4 acc[4] = {z, z, z, z};
  #pragma unroll
  for (int t4 = 0; t4 < 4; t4++){
    bf16x8 b0 = *(const bf16x8*)&wt[t4 * 16 + cb][kg];
    bf16x8 b1 = *(const bf16x8*)&wt[t4 * 16 + cb][32 + kg];
    acc[t4] = __builtin_amdgcn_mfma_f32_16x16x32_bf16(a0, b0, acc[t4], 0, 0, 0);
    acc[t4] = __builtin_amdgcn_mfma_f32_16x16x32_bf16(a1, b1, acc[t4], 0, 0, 0);
  }
  #pragma unroll
  for (int t4 = 0; t4 < 4; t4++){
    #pragma unroll
    for (int i = 0; i < 4; i++){
      int n = n0 + w * 16 + rb + i;
      if (n < NN) outb[(size_t)n * 64 + t4 * 16 + cb] = f2bf(acc[t4][i]);
    }
  }
}

// ---------------- edge gather (unchanged): lane-parallel adjacency + 4-deep unroll ----------------
__global__ __launch_bounds__(256) void k_gather(const u32* __restrict__ edges, const u32* __restrict__ rowpR,
                                                const u32* __restrict__ kvp, const u16* __restrict__ Qr,
                                                u16* __restrict__ Sr, float* __restrict__ alphaR){
  int wid = threadIdx.x >> 6, lane = threadIdx.x & 63;
  int n = blockIdx.x * 4 + wid;
  float q = bf2f(Qr[(size_t)n * 64 + lane]);
  u32 beg = rowpR[n], end = rowpR[n + 1];
  float sa = 0.f, aa = 0.f;
  const float inv_sqrt_d = 0.35355339059327373f;
  for (u32 base = beg; base < end; base += 64){
    u32 cnt = (end - base < 64u) ? (end - base) : 64u;
    u32 eidx = (base + (u32)lane < end) ? edges[base + lane] : 0u;
    u32 j = 0;
    for (; j + 4 <= cnt; j += 4){
      int s0 = __shfl((int)eidx, (int)j);
      int s1 = __shfl((int)eidx, (int)j + 1);
      int s2 = __shfl((int)eidx, (int)j + 2);
      int s3 = __shfl((int)eidx, (int)j + 3);
      u32 w0 = kvp[(size_t)s0 * 64 + lane];
      u32 w1 = kvp[(size_t)s1 * 64 + lane];
      u32 w2 = kvp[(size_t)s2 * 64 + lane];
      u32 w3 = kvp[(size_t)s3 * 64 + lane];
      float p0 = q * bf2f((u16)(w0 & 0xFFFFu));
      float p1 = q * bf2f((u16)(w1 & 0xFFFFu));
      float p2 = q * bf2f((u16)(w2 & 0xFFFFu));
      float p3 = q * bf2f((u16)(w3 & 0xFFFFu));
      p0 += __shfl_xor(p0, 1); p1 += __shfl_xor(p1, 1); p2 += __shfl_xor(p2, 1); p3 += __shfl_xor(p3, 1);
      p0 += __shfl_xor(p0, 2); p1 += __shfl_xor(p1, 2); p2 += __shfl_xor(p2, 2); p3 += __shfl_xor(p3, 2);
      p0 += __shfl_xor(p0, 4); p1 += __shfl_xor(p1, 4); p2 += __shfl_xor(p2, 4); p3 += __shfl_xor(p3, 4);
      float e0 = p0 * inv_sqrt_d; e0 = (e0 > 0.f) ? e0 : 0.01f * e0;
      float e1 = p1 * inv_sqrt_d; e1 = (e1 > 0.f) ? e1 : 0.01f * e1;
      float e2 = p2 * inv_sqrt_d; e2 = (e2 > 0.f) ? e2 : 0.01f * e2;
      float e3 = p3 * inv_sqrt_d; e3 = (e3 > 0.f) ? e3 : 0.01f * e3;
      aa += (e0 + e1) + (e2 + e3);
      sa += (bf2f((u16)(w0 >> 16)) + bf2f((u16)(w1 >> 16))) +
            (bf2f((u16)(w2 >> 16)) + bf2f((u16)(w3 >> 16)));
    }
    for (; j < cnt; ++j){
      int s = __shfl((int)eidx, (int)j);
      u32 w = kvp[(size_t)s * 64 + lane];
      float p = q * bf2f((u16)(w & 0xFFFFu));
      p += __shfl_xor(p, 1);
      p += __shfl_xor(p, 2);
      p += __shfl_xor(p, 4);
      float e = p * inv_sqrt_d;
      e = (e > 0.f) ? e : 0.01f * e;
      aa += e;
      sa += bf2f((u16)(w >> 16));
    }
  }
  Sr[(size_t)n * 64 + lane] = f2bf(sa);
  if ((lane & 7) == 0) alphaR[(size_t)n * 8 + (lane >> 3)] = aa;
}

// ---------------- column softmax stats over N per (r,h) ----------------
__global__ __launch_bounds__(256) void k_stats1(const float* __restrict__ alpha, float2* __restrict__ part){
  int col = blockIdx.x;
  int r = col >> 3, h = col & 7;
  int chunk = blockIdx.y;
  const int per = (NN + 31) / 32;
  int nbeg = chunk * per;
  int nend = nbeg + per; if (nend > NN) nend = NN;
  int t = threadIdx.x;
  float m = -1e30f, s = 0.f;
  for (int n = nbeg + t; n < nend; n += 256){
    float a = alpha[((size_t)r * NN + n) * 8 + h];
    if (a > m){ s *= expf(m - a); m = a; }
    s += expf(a - m);
  }
  __shared__ float sm[256], ss[256];
  sm[t] = m; ss[t] = s; __syncthreads();
  for (int off = 128; off > 0; off >>= 1){
    if (t < off){
      float m2 = sm[t + off], s2 = ss[t + off];
      float M = fmaxf(sm[t], m2);
      ss[t] = ss[t] * expf(sm[t] - M) + s2 * expf(m2 - M);
      sm[t] = M;
    }
    __syncthreads();
  }
  if (t == 0) part[col * 32 + chunk] = make_float2(sm[0], ss[0]);
}

__global__ void k_stats2(const float2* __restrict__ part, float2* __restrict__ fin){
  int col = threadIdx.x;
  if (col < 32){
    float M = -1e30f, S = 0.f;
    for (int i = 0; i < 32; i++){
      float2 p = part[col * 32 + i];
      float Mn = fmaxf(M, p.x);
      S = S * expf(M - Mn) + p.y * expf(p.x - Mn);
      M = Mn;
    }
    fin[col] = make_float2(M, 1.f / S);
  }
}

// ---------------- message MFMA GEMM with fused alpha apply ----------------
__global__ __launch_bounds__(256) void k_msg(const u16* __restrict__ S, const float* __restrict__ alpha,
                                             const float2* __restrict__ fin, const u16* __restrict__ pwCat,
                                             u16* __restrict__ stacked){
  __shared__ u16 xa[64][72];
  __shared__ u16 wt[64][72];
  int r = blockIdx.y;
  int t = threadIdx.x;
  int n0 = blockIdx.x * 64;
  { // stage A = (alpha ⊙ S) -> bf16
    int row = t >> 2, c0 = (t & 3) * 16;
    int n = n0 + row;
    int na = (n < NN) ? n : (NN - 1);
    int h0 = c0 >> 3;
    float2 f0 = fin[r * 8 + h0];
    float2 f1 = fin[r * 8 + h0 + 1];
    float a0 = alpha[((size_t)r * NN + na) * 8 + h0];
    float a1 = alpha[((size_t)r * NN + na) * 8 + h0 + 1];
    float w0 = expf(a0 - f0.x) * f0.y;
    float w1 = expf(a1 - f1.x) * f1.y;
    const u32* sp = (const u32*)(S + ((size_t)r * NN + na) * 64 + c0);
    #pragma unroll
    for (int jj = 0; jj < 8; jj++){
      u32 bts = sp[jj];
      float wm = (jj < 4) ? w0 : w1;
      ushort2 o;
      o.x = f2bf(bf2f((u16)(bts & 0xFFFFu)) * wm);
      o.y = f2bf(bf2f((u16)(bts >> 16)) * wm);
      *(ushort2*)&xa[row][c0 + jj * 2] = o;
    }
  }
  {
    const u32* p0 = (const u32*)(pwCat + (size_t)r * 4096);
    for (int idx = t; idx < 2048; idx += 256){
      int out = idx >> 5, cc = idx & 31;
      *(u32*)&wt[out][cc * 2] = p0[idx];
    }
  }
  __syncthreads();
  int w = t >> 6, lane = t & 63;
  int ra = w * 16 + (lane & 15);
  int kg = (lane >> 4) * 8;
  int cb = lane & 15;
  int rb = (lane >> 4) * 4;
  bf16x8 a0 = *(const bf16x8*)&xa[ra][kg];
  bf16x8 a1 = *(const bf16x8*)&xa[ra][32 + kg];
  f32x4 z = {0.f, 0.f, 0.f, 0.f};
  f32x4 acc[4] = {z, z, z, z};
  #pragma unroll
  for (int t4 = 0; t4 < 4; t4++){
    bf16x8 b0 = *(const bf16x8*)&wt[t4 * 16 + cb][kg];
    bf16x8 b1 = *(const bf16x8*)&wt[t4 * 16 + cb][32 + kg];
    acc[t4] = __builtin_amdgcn_mfma_f32_16x16x32_bf16(a0, b0, acc[t4], 0, 0, 0);
    acc[t4] = __builtin_amdgcn_mfma_f32_16x16x32_bf16(a1, b1, acc[t4], 0, 0, 0);
  }
  #pragma unroll
  for (int t4 = 0; t4 < 4; t4++){
    #pragma unroll
    for (int i = 0; i < 4; i++){
      int n = n0 + w * 16 + rb + i;
      if (n < NN) stacked[((size_t)r * NN + n) * 64 + t4 * 16 + cb] = f2bf(acc[t4][i]);
    }
  }
}

// ---------------- semantic attn + gelu + residual + LN (streaming + shfl) ----------------
__global__ __launch_bounds__(256) void k_final(const u16* __restrict__ stacked, const u16* __restrict__ selfb,
                                               const float* __restrict__ xin,
                                               const float* __restrict__ semw, const float* __restrict__ semb,
                                               const float* __restrict__ lng, const float* __restrict__ lnb,
                                               float* __restrict__ xout){
  int t = threadIdx.x;
  int wid = t >> 6, lane = t & 63;
  int n = blockIdx.x * 4 + wid;
  float st[4];
  #pragma unroll
  for (int r = 0; r < 4; r++) st[r] = bf2f(stacked[((size_t)r * NN + n) * 64 + lane]);
  float sw = semw[lane];
  float lg[4];
  #pragma unroll
  for (int r = 0; r < 4; r++){
    float p = st[r] * sw;
    #pragma unroll
    for (int o = 1; o < 64; o <<= 1) p += __shfl_xor(p, o);
    lg[r] = p + semb[0];
  }
  float mx = fmaxf(fmaxf(lg[0], lg[1]), fmaxf(lg[2], lg[3]));
  float e0 = expf(lg[0] - mx), e1 = expf(lg[1] - mx), e2 = expf(lg[2] - mx), e3 = expf(lg[3] - mx);
  float inv = 1.f / (e0 + e1 + e2 + e3);
  float agg = (e0 * st[0] + e1 * st[1] + e2 * st[2] + e3 * st[3]) * inv;
  float pre = bf2f(selfb[(size_t)n * 64 + lane]) + agg;
  float ge = 0.5f * pre * (1.f + erff(pre * 0.70710678118654752f));
  float y = xin[(size_t)n * 64 + lane] + ge;
  float mu = y;
  #pragma unroll
  for (int o = 1; o < 64; o <<= 1) mu += __shfl_xor(mu, o);
  mu *= (1.f / 64.f);
  float d = y - mu;
  float vv = d * d;
  #pragma unroll
  for (int o = 1; o < 64; o <<= 1) vv += __shfl_xor(vv, o);
  vv *= (1.f / 64.f);
  xout[(size_t)n * 64 + lane] = d * rsqrtf(vv + 1e-5f) * lng[lane] + lnb[lane];
}

extern "C" void kernel_launch(void* const* d_in, const int* in_sizes, int n_in,
                              void* d_out, int out_size, void* d_ws, size_t ws_size,
                              hipStream_t stream){
  const float* x0    = (const float*)d_in[0];
  const int*   eidx  = (const int*)d_in[1];
  const int*   etyp  = (const int*)d_in[2];
  const float* WQ    = (const float*)d_in[3];
  const float* WK    = (const float*)d_in[4];
  const float* WV    = (const float*)d_in[5];
  const float* Wcat  = (const float*)d_in[6];
  const float* semw  = (const float*)d_in[7];
  const float* semb  = (const float*)d_in[8];
  const float* Wself = (const float*)d_in[9];
  const float* lng   = (const float*)d_in[10];
  const float* lnb   = (const float*)d_in[11];
  float* out = (float*)d_out;
  char* ws = (char*)d_ws;

  const int* srcArr = eidx;        // edge_index row 0 = src (j)
  const int* dstArr = eidx + EE;   // row 1 = dst (i)

  u32*  kvp      = (u32*)(ws + OFF_KV);
  u16*  selfb    = (u16*)(ws + OFF_KV);    // aliases kvp after last gather
  u16*  Qb       = (u16*)(ws + OFF_Q);
  u16*  stackedB = (u16*)(ws + OFF_Q);     // aliases dead Q after gathers
  u16*  Sb       = (u16*)(ws + OFF_S);
  u64*  bstore   = (u64*)(ws + OFF_S);     // aliases S during CSR build
  float* alphaB  = (float*)(ws + OFF_AL);
  u16*  pwB      = (u16*)(ws + OFF_PW);
  float2* part   = (float2*)(ws + OFF_PART);
  float2* fin    = (float2*)(ws + OFF_FIN);
  u32* bcnt   = (u32*)(ws + OFF_BCNT);
  u32* bstart = (u32*)(ws + OFF_BST);
  u32* rowp   = (u32*)(ws + OFF_ROWP);
  u32* edges  = (u32*)(ws + OFF_EDG);

  // ---- CSR segmented by (relation, dst) via bounded bucket sort ----
  k_binit<<<(NBUCK + 255) / 256, 256, 0, stream>>>(bcnt);
  k_bucket<<<1024, 256, 0, stream>>>(srcArr, dstArr, etyp, bcnt, bstore);
  k_bscan<<<1, 1024, 0, stream>>>(bcnt, bstart, rowp);
  k_bsort<<<NBUCK, 256, 0, stream>>>(bstore, bcnt, bstart, rowp, edges);
  k_repackbf<<<(2 * 17 * 4096 + 255) / 256, 256, 0, stream>>>(WQ, WK, WV, Wcat, Wself, pwB);

  for (int l = 0; l < 2; l++){
    const float* xcur = (l == 0) ? x0 : out;
    const u16* pwL = pwB + (size_t)l * 17 * 4096;
    for (int r = 0; r < 4; r++){
      k_qkv<<<1563, 256, 0, stream>>>(xcur, pwL + (size_t)r * 4096, pwL + (size_t)(4 + r) * 4096,
                                      pwL + (size_t)(8 + r) * 4096, Qb + (size_t)r * NN * 64, kvp);
      k_gather<<<NN / 4, 256, 0, stream>>>(edges, rowp + (size_t)r * NN, kvp,
                                           Qb + (size_t)r * NN * 64,
                                           Sb + (size_t)r * NN * 64,
                                           alphaB + (size_t)r * NN * 8);
    }
    k_self<<<1563, 256, 0, stream>>>(xcur, pwL + (size_t)12 * 4096, selfb);
    k_stats1<<<dim3(32, 32), 256, 0, stream>>>(alphaB, part);
    k_stats2<<<1, 64, 0, stream>>>(part, fin);
    k_msg<<<dim3(1563, 4), 256, 0, stream>>>(Sb, alphaB, fin, pwL + (size_t)13 * 4096, stackedB);
    k_final<<<NN / 4, 256, 0, stream>>>(stackedB, selfb, xcur,
                                        semw + l * 64, semb + l, lng + l * 64, lnb + l * 64, out);
  }
  (void)in_sizes; (void)n_in; (void)out_size; (void)ws_size;
}

// Round 5
// 749.679 us; speedup vs baseline: 1.6317x; 1.1837x over previous
//
#include <hip/hip_runtime.h>
#include <hip/hip_bf16.h>

#define NN 100000
#define EE 1600000
#define RRR 4
#define HHH 8
#define NT 400000      // RRR * NN
#define NBUCK 12500    // NT / 32 (32 segments per bucket)
#define BCAP 256       // mean fill 128, sigma ~11 -> 11-sigma headroom

typedef unsigned int u32;
typedef unsigned short u16;
typedef unsigned long long u64;
typedef __attribute__((ext_vector_type(8))) short bf16x8;
typedef __attribute__((ext_vector_type(4))) float f32x4;

// ---------------- workspace layout (bytes), total ~149 MB ----------------
static constexpr size_t OFF_KV   = 0;              // u32 [N][64] packed KV (per-relation reuse); bf16 self aliases later
static constexpr size_t OFF_Q    = 25600000;       // bf16 [4][N][64] Q; 'stacked' aliases after gathers
static constexpr size_t OFF_S    = 76800000;       // bf16 [4][N][64] V-sums; bstore u64[NBUCK*BCAP]=25.6MB aliases during CSR build
static constexpr size_t OFF_AL   = 128000000;      // f32  [4][N][8] energy sums
static constexpr size_t OFF_PW   = 140800000;      // u16  [2][17][64][64] bf16 weights, [out][c] layout
static constexpr size_t OFF_PART = 141100000;      // float2 [32][32]
static constexpr size_t OFF_FIN  = 141110000;      // float2 [32]
static constexpr size_t OFF_BCNT = 141111008;      // u32 [NBUCK]
static constexpr size_t OFF_BST  = 141161008;      // u32 [NBUCK]
static constexpr size_t OFF_ROWP = 141211008;      // u32 [NT+1]
static constexpr size_t OFF_EDG  = 142812012;      // u32 [E]  (4B-aligned)

__device__ inline u16 f2bf(float f){
  union { __hip_bfloat16 h; u16 u; } cv; cv.h = __float2bfloat16(f); return cv.u;
}
__device__ inline float bf2f(u16 u){ return __uint_as_float(((u32)u) << 16); }

// ---------------- CSR build: fine buckets + per-bucket LDS counting sort ----------------
__global__ __launch_bounds__(256) void k_binit(u32* __restrict__ bcnt){
  int i = blockIdx.x * 256 + threadIdx.x;
  if (i < NBUCK) bcnt[i] = 0u;
}

__global__ __launch_bounds__(256) void k_bucket(const int* __restrict__ src, const int* __restrict__ dst,
                                                const int* __restrict__ typ, u32* __restrict__ bcnt,
                                                u64* __restrict__ bstore){
  for (int e = blockIdx.x * blockDim.x + threadIdx.x; e < EE; e += gridDim.x * blockDim.x){
    int seg = typ[e] * NN + dst[e];
    int b = seg >> 5;
    u32 pos = atomicAdd(&bcnt[b], 1u);
    if (pos < BCAP) bstore[(size_t)b * BCAP + pos] = ((u64)(u32)seg << 32) | (u32)src[e];
  }
}

// single block, 1024 threads, 13 buckets per thread
__global__ __launch_bounds__(1024) void k_bscan(const u32* __restrict__ bcnt, u32* __restrict__ bstart,
                                                u32* __restrict__ rowp){
  __shared__ u32 tmp[1024];
  int t = threadIdx.x;
  const int PER = (NBUCK + 1023) / 1024;   // 13
  u32 loc[PER];
  u32 s = 0;
  #pragma unroll
  for (int i = 0; i < PER; i++){
    int idx = t * PER + i;
    u32 v = (idx < NBUCK) ? min(bcnt[idx], (u32)BCAP) : 0u;
    loc[i] = s; s += v;
  }
  tmp[t] = s; __syncthreads();
  for (int off = 1; off < 1024; off <<= 1){
    u32 add = (t >= off) ? tmp[t - off] : 0u; __syncthreads();
    tmp[t] += add; __syncthreads();
  }
  u32 base = tmp[t] - s;
  #pragma unroll
  for (int i = 0; i < PER; i++){
    int idx = t * PER + i;
    if (idx < NBUCK) bstart[idx] = base + loc[i];
  }
  if (t == 0) rowp[NT] = EE;
}

__global__ __launch_bounds__(256) void k_bsort(const u64* __restrict__ bstore, const u32* __restrict__ bcnt,
                                               const u32* __restrict__ bstart, u32* __restrict__ rowp,
                                               u32* __restrict__ edges){
  __shared__ u16 skey[BCAP];
  __shared__ u32 ssrc[BCAP];
  __shared__ u32 off[32], cur[32], excl[32];
  int b = blockIdx.x, t = threadIdx.x;
  u32 cnt = min(bcnt[b], (u32)BCAP);
  u32 base = bstart[b];
  if (t < 32) off[t] = 0u;
  __syncthreads();
  for (u32 i = t; i < cnt; i += 256){
    u64 v = bstore[(size_t)b * BCAP + i];
    skey[i] = (u16)((v >> 32) & 31u);
    ssrc[i] = (u32)v;
    atomicAdd(&off[(v >> 32) & 31u], 1u);
  }
  __syncthreads();
  if (t == 0){
    u32 acc = 0;
    #pragma unroll
    for (int k = 0; k < 32; k++){ u32 c = off[k]; excl[k] = acc; cur[k] = acc; acc += c; }
  }
  __syncthreads();
  if (t < 32){
    int seg = b * 32 + t;
    if (seg < NT) rowp[seg] = base + excl[t];
  }
  __syncthreads();
  for (u32 i = t; i < cnt; i += 256){
    u32 p = atomicAdd(&cur[skey[i]], 1u);
    edges[base + p] = ssrc[i];
  }
}

// ---------------- weight repack (both layers): pwB[l][mat][out][c] bf16 ----------------
// mats 0-3 Q r0-3 ; 4-7 K ; 8-11 V ; 12 W_self ; 13-16 Wcat r0-3
__global__ __launch_bounds__(256) void k_repackbf(const float* __restrict__ WQ, const float* __restrict__ WK,
                                                  const float* __restrict__ WV, const float* __restrict__ Wcat,
                                                  const float* __restrict__ Wself, u16* __restrict__ pwB){
  int t = blockIdx.x * 256 + threadIdx.x;
  if (t >= 2 * 17 * 4096) return;
  int l = t / (17 * 4096), rem = t % (17 * 4096);
  int mat = rem >> 12, idx = rem & 4095;
  int out = idx >> 6, c = idx & 63;
  float v;
  if (mat < 12){
    int kind = mat >> 2, r = mat & 3;
    int h = out >> 3, d = out & 7;
    const float* Wsrc = (kind == 0) ? WQ : (kind == 1) ? WK : WV;
    v = Wsrc[((((l * RRR + r) * HHH + h) * 64) + c) * 8 + d];
  } else if (mat == 12){
    v = Wself[(l * 64 + c) * 64 + out];
  } else {
    int r = mat - 13;
    v = Wcat[(((l * RRR + r) * 64) + c) * 64 + out];
  }
  pwB[t] = f2bf(v);
}

// ---------------- MFMA helpers ----------------
// A-frag (16x32): row = lane&15, k = (lane>>4)*8 + j (8 consecutive)
// B-frag (32x16): col = lane&15, k = (lane>>4)*8 + j  -> read from [out][c] layout
// D (16x16): col = lane&15, row = (lane>>4)*4 + reg

// ---------------- Q,K,V MFMA GEMM for one relation ----------------
__global__ __launch_bounds__(256) void k_qkv(const float* __restrict__ x,
                                             const u16* __restrict__ pwQ, const u16* __restrict__ pwK,
                                             const u16* __restrict__ pwV,
                                             u16* __restrict__ Qr, u32* __restrict__ kvp){
  __shared__ u16 xa[64][72];
  __shared__ u16 wt[3][64][72];
  int t = threadIdx.x;
  int n0 = blockIdx.x * 64;
  { // stage x -> bf16
    int row = t >> 2, c0 = (t & 3) * 16;
    int n = n0 + row;
    float4 v0 = {}, v1 = {}, v2 = {}, v3 = {};
    if (n < NN){
      const float4* xp = (const float4*)(x + (size_t)n * 64 + c0);
      v0 = xp[0]; v1 = xp[1]; v2 = xp[2]; v3 = xp[3];
    }
    ushort4* dp = (ushort4*)&xa[row][c0];
    dp[0] = make_ushort4(f2bf(v0.x), f2bf(v0.y), f2bf(v0.z), f2bf(v0.w));
    dp[1] = make_ushort4(f2bf(v1.x), f2bf(v1.y), f2bf(v1.z), f2bf(v1.w));
    dp[2] = make_ushort4(f2bf(v2.x), f2bf(v2.y), f2bf(v2.z), f2bf(v2.w));
    dp[3] = make_ushort4(f2bf(v3.x), f2bf(v3.y), f2bf(v3.z), f2bf(v3.w));
  }
  { // stage weights (already bf16, [out][c])
    const u32* p0 = (const u32*)pwQ;
    const u32* p1 = (const u32*)pwK;
    const u32* p2 = (const u32*)pwV;
    for (int idx = t; idx < 3 * 2048; idx += 256){
      int m = idx >> 11, rem = idx & 2047;
      int out = rem >> 5, cc = rem & 31;
      u32 w = (m == 0) ? p0[rem] : (m == 1) ? p1[rem] : p2[rem];
      *(u32*)&wt[m][out][cc * 2] = w;
    }
  }
  __syncthreads();
  int w = t >> 6, lane = t & 63;
  int ra = w * 16 + (lane & 15);
  int kg = (lane >> 4) * 8;
  int cb = lane & 15;
  int rb = (lane >> 4) * 4;
  bf16x8 a0 = *(const bf16x8*)&xa[ra][kg];
  bf16x8 a1 = *(const bf16x8*)&xa[ra][32 + kg];
  f32x4 z = {0.f, 0.f, 0.f, 0.f};
  { // Q
    f32x4 acc[4] = {z, z, z, z};
    #pragma unroll
    for (int t4 = 0; t4 < 4; t4++){
      bf16x8 b0 = *(const bf16x8*)&wt[0][t4 * 16 + cb][kg];
      bf16x8 b1 = *(const bf16x8*)&wt[0][t4 * 16 + cb][32 + kg];
      acc[t4] = __builtin_amdgcn_mfma_f32_16x16x32_bf16(a0, b0, acc[t4], 0, 0, 0);
      acc[t4] = __builtin_amdgcn_mfma_f32_16x16x32_bf16(a1, b1, acc[t4], 0, 0, 0);
    }
    #pragma unroll
    for (int t4 = 0; t4 < 4; t4++){
      #pragma unroll
      for (int i = 0; i < 4; i++){
        int n = n0 + w * 16 + rb + i;
        if (n < NN) Qr[(size_t)n * 64 + t4 * 16 + cb] = f2bf(acc[t4][i]);
      }
    }
  }
  { // K,V packed
    f32x4 ak[4] = {z, z, z, z};
    f32x4 av[4] = {z, z, z, z};
    #pragma unroll
    for (int t4 = 0; t4 < 4; t4++){
      bf16x8 bk0 = *(const bf16x8*)&wt[1][t4 * 16 + cb][kg];
      bf16x8 bk1 = *(const bf16x8*)&wt[1][t4 * 16 + cb][32 + kg];
      bf16x8 bv0 = *(const bf16x8*)&wt[2][t4 * 16 + cb][kg];
      bf16x8 bv1 = *(const bf16x8*)&wt[2][t4 * 16 + cb][32 + kg];
      ak[t4] = __builtin_amdgcn_mfma_f32_16x16x32_bf16(a0, bk0, ak[t4], 0, 0, 0);
      ak[t4] = __builtin_amdgcn_mfma_f32_16x16x32_bf16(a1, bk1, ak[t4], 0, 0, 0);
      av[t4] = __builtin_amdgcn_mfma_f32_16x16x32_bf16(a0, bv0, av[t4], 0, 0, 0);
      av[t4] = __builtin_amdgcn_mfma_f32_16x16x32_bf16(a1, bv1, av[t4], 0, 0, 0);
    }
    #pragma unroll
    for (int t4 = 0; t4 < 4; t4++){
      #pragma unroll
      for (int i = 0; i < 4; i++){
        int n = n0 + w * 16 + rb + i;
        if (n < NN) kvp[(size_t)n * 64 + t4 * 16 + cb] = (u32)f2bf(ak[t4][i]) | ((u32)f2bf(av[t4][i]) << 16);
      }
    }
  }
}

// ---------------- self MFMA GEMM (1 mat, u16 out) ----------------
__global__ __launch_bounds__(256) void k_self(const float* __restrict__ x, const u16* __restrict__ pwS,
                                              u16* __restrict__ outb){
  __shared__ u16 xa[64][72];
  __shared__ u16 wt[64][72];
  int t = threadIdx.x;
  int n0 = blockIdx.x * 64;
  {
    int row = t >> 2, c0 = (t & 3) * 16;
    int n = n0 + row;
    float4 v0 = {}, v1 = {}, v2 = {}, v3 = {};
    if (n < NN){
      const float4* xp = (const float4*)(x + (size_t)n * 64 + c0);
      v0 = xp[0]; v1 = xp[1]; v2 = xp[2]; v3 = xp[3];
    }
    ushort4* dp = (ushort4*)&xa[row][c0];
    dp[0] = make_ushort4(f2bf(v0.x), f2bf(v0.y), f2bf(v0.z), f2bf(v0.w));
    dp[1] = make_ushort4(f2bf(v1.x), f2bf(v1.y), f2bf(v1.z), f2bf(v1.w));
    dp[2] = make_ushort4(f2bf(v2.x), f2bf(v2.y), f2bf(v2.z), f2bf(v2.w));
    dp[3] = make_ushort4(f2bf(v3.x), f2bf(v3.y), f2bf(v3.z), f2bf(v3.w));
  }
  {
    const u32* p0 = (const u32*)pwS;
    for (int idx = t; idx < 2048; idx += 256){
      int out = idx >> 5, cc = idx & 31;
      *(u32*)&wt[out][cc * 2] = p0[idx];
    }
  }
  __syncthreads();
  int w = t >> 6, lane = t & 63;
  int ra = w * 16 + (lane & 15);
  int kg = (lane >> 4) * 8;
  int cb = lane & 15;
  int rb = (lane >> 4) * 4;
  bf16x8 a0 = *(const bf16x8*)&xa[ra][kg];
  bf16x8 a1 = *(const bf16x8*)&xa[ra][32 + kg];
  f32x4 z = {0.f, 0.f, 0.f, 0.f};
  f32x4 acc[4] = {z, z, z, z};
  #pragma unroll
  for (int t4 = 0; t4 < 4; t4++){
    bf16x8 b0 = *(const bf16x8*)&wt[t4 * 16 + cb][kg];
    bf16x8 b1 = *(const bf16x8*)&wt[t4 * 16 + cb][32 + kg];
    acc[t4] = __builtin_amdgcn_mfma_f32_16x16x32_bf16(a0, b0, acc[t4], 0, 0, 0);
    acc[t4] = __builtin_amdgcn_mfma_f32_16x16x32_bf16(a1, b1, acc[t4], 0, 0, 0);
  }
  #pragma unroll
  for (int t4 = 0; t4 < 4; t4++){
    #pragma unroll
    for (int i = 0; i < 4; i++){
      int n = n0 + w * 16 + rb + i;
      if (n < NN) outb[(size_t)n * 64 + t4 * 16 + cb] = f2bf(acc[t4][i]);
    }
  }
}

// ---------------- edge gather: lane-parallel adjacency + 4-deep unroll ----------------
__global__ __launch_bounds__(256) void k_gather(const u32* __restrict__ edges, const u32* __restrict__ rowpR,
                                                const u32* __restrict__ kvp, const u16* __restrict__ Qr,
                                                u16* __restrict__ Sr, float* __restrict__ alphaR){
  int wid = threadIdx.x >> 6, lane = threadIdx.x & 63;
  int n = blockIdx.x * 4 + wid;
  float q = bf2f(Qr[(size_t)n * 64 + lane]);
  u32 beg = rowpR[n], end = rowpR[n + 1];
  float sa = 0.f, aa = 0.f;
  const float inv_sqrt_d = 0.35355339059327373f;
  for (u32 base = beg; base < end; base += 64){
    u32 cnt = (end - base < 64u) ? (end - base) : 64u;
    u32 eidx = (base + (u32)lane < end) ? edges[base + lane] : 0u;
    u32 j = 0;
    for (; j + 4 <= cnt; j += 4){
      int s0 = __shfl((int)eidx, (int)j);
      int s1 = __shfl((int)eidx, (int)j + 1);
      int s2 = __shfl((int)eidx, (int)j + 2);
      int s3 = __shfl((int)eidx, (int)j + 3);
      u32 w0 = kvp[(size_t)s0 * 64 + lane];
      u32 w1 = kvp[(size_t)s1 * 64 + lane];
      u32 w2 = kvp[(size_t)s2 * 64 + lane];
      u32 w3 = kvp[(size_t)s3 * 64 + lane];
      float p0 = q * bf2f((u16)(w0 & 0xFFFFu));
      float p1 = q * bf2f((u16)(w1 & 0xFFFFu));
      float p2 = q * bf2f((u16)(w2 & 0xFFFFu));
      float p3 = q * bf2f((u16)(w3 & 0xFFFFu));
      p0 += __shfl_xor(p0, 1); p1 += __shfl_xor(p1, 1); p2 += __shfl_xor(p2, 1); p3 += __shfl_xor(p3, 1);
      p0 += __shfl_xor(p0, 2); p1 += __shfl_xor(p1, 2); p2 += __shfl_xor(p2, 2); p3 += __shfl_xor(p3, 2);
      p0 += __shfl_xor(p0, 4); p1 += __shfl_xor(p1, 4); p2 += __shfl_xor(p2, 4); p3 += __shfl_xor(p3, 4);
      float e0 = p0 * inv_sqrt_d; e0 = (e0 > 0.f) ? e0 : 0.01f * e0;
      float e1 = p1 * inv_sqrt_d; e1 = (e1 > 0.f) ? e1 : 0.01f * e1;
      float e2 = p2 * inv_sqrt_d; e2 = (e2 > 0.f) ? e2 : 0.01f * e2;
      float e3 = p3 * inv_sqrt_d; e3 = (e3 > 0.f) ? e3 : 0.01f * e3;
      aa += (e0 + e1) + (e2 + e3);
      sa += (bf2f((u16)(w0 >> 16)) + bf2f((u16)(w1 >> 16))) +
            (bf2f((u16)(w2 >> 16)) + bf2f((u16)(w3 >> 16)));
    }
    for (; j < cnt; ++j){
      int s = __shfl((int)eidx, (int)j);
      u32 w = kvp[(size_t)s * 64 + lane];
      float p = q * bf2f((u16)(w & 0xFFFFu));
      p += __shfl_xor(p, 1);
      p += __shfl_xor(p, 2);
      p += __shfl_xor(p, 4);
      float e = p * inv_sqrt_d;
      e = (e > 0.f) ? e : 0.01f * e;
      aa += e;
      sa += bf2f((u16)(w >> 16));
    }
  }
  Sr[(size_t)n * 64 + lane] = f2bf(sa);
  if ((lane & 7) == 0) alphaR[(size_t)n * 8 + (lane >> 3)] = aa;
}

// ---------------- column softmax stats over N per (r,h) ----------------
__global__ __launch_bounds__(256) void k_stats1(const float* __restrict__ alpha, float2* __restrict__ part){
  int col = blockIdx.x;
  int r = col >> 3, h = col & 7;
  int chunk = blockIdx.y;
  const int per = (NN + 31) / 32;
  int nbeg = chunk * per;
  int nend = nbeg + per; if (nend > NN) nend = NN;
  int t = threadIdx.x;
  float m = -1e30f, s = 0.f;
  for (int n = nbeg + t; n < nend; n += 256){
    float a = alpha[((size_t)r * NN + n) * 8 + h];
    if (a > m){ s *= expf(m - a); m = a; }
    s += expf(a - m);
  }
  __shared__ float sm[256], ss[256];
  sm[t] = m; ss[t] = s; __syncthreads();
  for (int off = 128; off > 0; off >>= 1){
    if (t < off){
      float m2 = sm[t + off], s2 = ss[t + off];
      float M = fmaxf(sm[t], m2);
      ss[t] = ss[t] * expf(sm[t] - M) + s2 * expf(m2 - M);
      sm[t] = M;
    }
    __syncthreads();
  }
  if (t == 0) part[col * 32 + chunk] = make_float2(sm[0], ss[0]);
}

__global__ void k_stats2(const float2* __restrict__ part, float2* __restrict__ fin){
  int col = threadIdx.x;
  if (col < 32){
    float M = -1e30f, S = 0.f;
    for (int i = 0; i < 32; i++){
      float2 p = part[col * 32 + i];
      float Mn = fmaxf(M, p.x);
      S = S * expf(M - Mn) + p.y * expf(p.x - Mn);
      M = Mn;
    }
    fin[col] = make_float2(M, 1.f / S);
  }
}

// ---------------- message MFMA GEMM with fused alpha apply ----------------
__global__ __launch_bounds__(256) void k_msg(const u16* __restrict__ S, const float* __restrict__ alpha,
                                             const float2* __restrict__ fin, const u16* __restrict__ pwCat,
                                             u16* __restrict__ stacked){
  __shared__ u16 xa[64][72];
  __shared__ u16 wt[64][72];
  int r = blockIdx.y;
  int t = threadIdx.x;
  int n0 = blockIdx.x * 64;
  { // stage A = (alpha ⊙ S) -> bf16
    int row = t >> 2, c0 = (t & 3) * 16;
    int n = n0 + row;
    int na = (n < NN) ? n : (NN - 1);
    int h0 = c0 >> 3;
    float2 f0 = fin[r * 8 + h0];
    float2 f1 = fin[r * 8 + h0 + 1];
    float a0 = alpha[((size_t)r * NN + na) * 8 + h0];
    float a1 = alpha[((size_t)r * NN + na) * 8 + h0 + 1];
    float w0 = expf(a0 - f0.x) * f0.y;
    float w1 = expf(a1 - f1.x) * f1.y;
    const u32* sp = (const u32*)(S + ((size_t)r * NN + na) * 64 + c0);
    #pragma unroll
    for (int jj = 0; jj < 8; jj++){
      u32 bts = sp[jj];
      float wm = (jj < 4) ? w0 : w1;
      ushort2 o;
      o.x = f2bf(bf2f((u16)(bts & 0xFFFFu)) * wm);
      o.y = f2bf(bf2f((u16)(bts >> 16)) * wm);
      *(ushort2*)&xa[row][c0 + jj * 2] = o;
    }
  }
  {
    const u32* p0 = (const u32*)(pwCat + (size_t)r * 4096);
    for (int idx = t; idx < 2048; idx += 256){
      int out = idx >> 5, cc = idx & 31;
      *(u32*)&wt[out][cc * 2] = p0[idx];
    }
  }
  __syncthreads();
  int w = t >> 6, lane = t & 63;
  int ra = w * 16 + (lane & 15);
  int kg = (lane >> 4) * 8;
  int cb = lane & 15;
  int rb = (lane >> 4) * 4;
  bf16x8 a0 = *(const bf16x8*)&xa[ra][kg];
  bf16x8 a1 = *(const bf16x8*)&xa[ra][32 + kg];
  f32x4 z = {0.f, 0.f, 0.f, 0.f};
  f32x4 acc[4] = {z, z, z, z};
  #pragma unroll
  for (int t4 = 0; t4 < 4; t4++){
    bf16x8 b0 = *(const bf16x8*)&wt[t4 * 16 + cb][kg];
    bf16x8 b1 = *(const bf16x8*)&wt[t4 * 16 + cb][32 + kg];
    acc[t4] = __builtin_amdgcn_mfma_f32_16x16x32_bf16(a0, b0, acc[t4], 0, 0, 0);
    acc[t4] = __builtin_amdgcn_mfma_f32_16x16x32_bf16(a1, b1, acc[t4], 0, 0, 0);
  }
  #pragma unroll
  for (int t4 = 0; t4 < 4; t4++){
    #pragma unroll
    for (int i = 0; i < 4; i++){
      int n = n0 + w * 16 + rb + i;
      if (n < NN) stacked[((size_t)r * NN + n) * 64 + t4 * 16 + cb] = f2bf(acc[t4][i]);
    }
  }
}

// ---------------- semantic attn + gelu + residual + LN (streaming + shfl) ----------------
__global__ __launch_bounds__(256) void k_final(const u16* __restrict__ stacked, const u16* __restrict__ selfb,
                                               const float* __restrict__ xin,
                                               const float* __restrict__ semw, const float* __restrict__ semb,
                                               const float* __restrict__ lng, const float* __restrict__ lnb,
                                               float* __restrict__ xout){
  int t = threadIdx.x;
  int wid = t >> 6, lane = t & 63;
  int n = blockIdx.x * 4 + wid;
  float st[4];
  #pragma unroll
  for (int r = 0; r < 4; r++) st[r] = bf2f(stacked[((size_t)r * NN + n) * 64 + lane]);
  float sw = semw[lane];
  float lg[4];
  #pragma unroll
  for (int r = 0; r < 4; r++){
    float p = st[r] * sw;
    #pragma unroll
    for (int o = 1; o < 64; o <<= 1) p += __shfl_xor(p, o);
    lg[r] = p + semb[0];
  }
  float mx = fmaxf(fmaxf(lg[0], lg[1]), fmaxf(lg[2], lg[3]));
  float e0 = expf(lg[0] - mx), e1 = expf(lg[1] - mx), e2 = expf(lg[2] - mx), e3 = expf(lg[3] - mx);
  float inv = 1.f / (e0 + e1 + e2 + e3);
  float agg = (e0 * st[0] + e1 * st[1] + e2 * st[2] + e3 * st[3]) * inv;
  float pre = bf2f(selfb[(size_t)n * 64 + lane]) + agg;
  float ge = 0.5f * pre * (1.f + erff(pre * 0.70710678118654752f));
  float y = xin[(size_t)n * 64 + lane] + ge;
  float mu = y;
  #pragma unroll
  for (int o = 1; o < 64; o <<= 1) mu += __shfl_xor(mu, o);
  mu *= (1.f / 64.f);
  float d = y - mu;
  float vv = d * d;
  #pragma unroll
  for (int o = 1; o < 64; o <<= 1) vv += __shfl_xor(vv, o);
  vv *= (1.f / 64.f);
  xout[(size_t)n * 64 + lane] = d * rsqrtf(vv + 1e-5f) * lng[lane] + lnb[lane];
}

extern "C" void kernel_launch(void* const* d_in, const int* in_sizes, int n_in,
                              void* d_out, int out_size, void* d_ws, size_t ws_size,
                              hipStream_t stream){
  const float* x0    = (const float*)d_in[0];
  const int*   eidx  = (const int*)d_in[1];
  const int*   etyp  = (const int*)d_in[2];
  const float* WQ    = (const float*)d_in[3];
  const float* WK    = (const float*)d_in[4];
  const float* WV    = (const float*)d_in[5];
  const float* Wcat  = (const float*)d_in[6];
  const float* semw  = (const float*)d_in[7];
  const float* semb  = (const float*)d_in[8];
  const float* Wself = (const float*)d_in[9];
  const float* lng   = (const float*)d_in[10];
  const float* lnb   = (const float*)d_in[11];
  float* out = (float*)d_out;
  char* ws = (char*)d_ws;

  const int* srcArr = eidx;        // edge_index row 0 = src (j)
  const int* dstArr = eidx + EE;   // row 1 = dst (i)

  u32*  kvp      = (u32*)(ws + OFF_KV);
  u16*  selfb    = (u16*)(ws + OFF_KV);    // aliases kvp after last gather
  u16*  Qb       = (u16*)(ws + OFF_Q);
  u16*  stackedB = (u16*)(ws + OFF_Q);     // aliases dead Q after gathers
  u16*  Sb       = (u16*)(ws + OFF_S);
  u64*  bstore   = (u64*)(ws + OFF_S);     // aliases S during CSR build
  float* alphaB  = (float*)(ws + OFF_AL);
  u16*  pwB      = (u16*)(ws + OFF_PW);
  float2* part   = (float2*)(ws + OFF_PART);
  float2* fin    = (float2*)(ws + OFF_FIN);
  u32* bcnt   = (u32*)(ws + OFF_BCNT);
  u32* bstart = (u32*)(ws + OFF_BST);
  u32* rowp   = (u32*)(ws + OFF_ROWP);
  u32* edges  = (u32*)(ws + OFF_EDG);

  // ---- CSR segmented by (relation, dst) via fine-bucket sort ----
  k_binit<<<(NBUCK + 255) / 256, 256, 0, stream>>>(bcnt);
  k_bucket<<<1024, 256, 0, stream>>>(srcArr, dstArr, etyp, bcnt, bstore);
  k_bscan<<<1, 1024, 0, stream>>>(bcnt, bstart, rowp);
  k_bsort<<<NBUCK, 256, 0, stream>>>(bstore, bcnt, bstart, rowp, edges);
  k_repackbf<<<(2 * 17 * 4096 + 255) / 256, 256, 0, stream>>>(WQ, WK, WV, Wcat, Wself, pwB);

  for (int l = 0; l < 2; l++){
    const float* xcur = (l == 0) ? x0 : out;
    const u16* pwL = pwB + (size_t)l * 17 * 4096;
    for (int r = 0; r < 4; r++){
      k_qkv<<<1563, 256, 0, stream>>>(xcur, pwL + (size_t)r * 4096, pwL + (size_t)(4 + r) * 4096,
                                      pwL + (size_t)(8 + r) * 4096, Qb + (size_t)r * NN * 64, kvp);
      k_gather<<<NN / 4, 256, 0, stream>>>(edges, rowp + (size_t)r * NN, kvp,
                                           Qb + (size_t)r * NN * 64,
                                           Sb + (size_t)r * NN * 64,
                                           alphaB + (size_t)r * NN * 8);
    }
    k_self<<<1563, 256, 0, stream>>>(xcur, pwL + (size_t)12 * 4096, selfb);
    k_stats1<<<dim3(32, 32), 256, 0, stream>>>(alphaB, part);
    k_stats2<<<1, 64, 0, stream>>>(part, fin);
    k_msg<<<dim3(1563, 4), 256, 0, stream>>>(Sb, alphaB, fin, pwL + (size_t)13 * 4096, stackedB);
    k_final<<<NN / 4, 256, 0, stream>>>(stackedB, selfb, xcur,
                                        semw + l * 64, semb + l, lng + l * 64, lnb + l * 64, out);
  }
  (void)in_sizes; (void)n_in; (void)out_size; (void)ws_size;
}

// Round 6
// 710.702 us; speedup vs baseline: 1.7212x; 1.0548x over previous
//
#include <hip/hip_runtime.h>
#include <hip/hip_bf16.h>

#define NN 100000
#define EE 1600000
#define RRR 4
#define HHH 8
#define NT 400000      // RRR * NN
#define GG 782         // ceil(NT / 512) coarse buckets (seg>>9)
#define SHIFT 9
#define NBLK 512       // phase-1 blocks
#define CHUNK 3125     // EE / NBLK exactly
#define BMAX 2560      // per-bucket cap (mean 2048, sigma 45 -> 11 sigma)

typedef unsigned int u32;
typedef unsigned short u16;
typedef __attribute__((ext_vector_type(8))) short bf16x8;
typedef __attribute__((ext_vector_type(4))) float f32x4;

// ---------------- workspace layout (bytes), total ~149.4 MB (<=152.6 proven safe) ----------------
static constexpr size_t OFF_KV   = 0;              // u32 [N][64] packed KV (per-relation reuse); bf16 self aliases later
static constexpr size_t OFF_Q    = 25600000;       // bf16 [4][N][64] Q; 'stacked' aliases after gathers
static constexpr size_t OFF_S    = 76800000;       // bf16 [4][N][64] V-sums; CSR temps alias during build
static constexpr size_t OFF_AL   = 128000000;      // f32  [4][N][8] energy sums
static constexpr size_t OFF_PW   = 140800000;      // u16  [2][17][64][64] bf16 weights, [out][c] layout
static constexpr size_t OFF_PART = 141100000;      // float2 [32][32]
static constexpr size_t OFF_FIN  = 141110000;      // float2 [32]
static constexpr size_t OFF_ROWP = 141365504;      // u32 [NT+1]
static constexpr size_t OFF_EDG  = 142965512;      // u32 [E]
// CSR temps alias the (dead-at-build-time) S region:
static constexpr size_t OFF_BSTORE = OFF_S;                  // u32 [E] = 6.4 MB
static constexpr size_t OFF_HIST   = OFF_S + 8000000;        // u32 [NBLK][GG] = 1.6 MB
static constexpr size_t OFF_OFFA   = OFF_S + 16000000;       // u32 [GG][NBLK] = 1.6 MB
static constexpr size_t OFF_BASE   = OFF_S + 24000000;       // u32 [GG+1]

__device__ inline u16 f2bf(float f){
  union { __hip_bfloat16 h; u16 u; } cv; cv.h = __float2bfloat16(f); return cv.u;
}
__device__ inline float bf2f(u16 u){ return __uint_as_float(((u32)u) << 16); }

// ---------------- CSR build: no-atomic two-pass partition + per-bucket counting sort ----------------
__global__ __launch_bounds__(256) void k_histA(const int* __restrict__ dst, const int* __restrict__ typ,
                                               u32* __restrict__ Hist){
  __shared__ u32 h[GG];
  int b = blockIdx.x, t = threadIdx.x;
  for (int g = t; g < GG; g += 256) h[g] = 0u;
  __syncthreads();
  int e0 = b * CHUNK;
  for (int e = e0 + t; e < e0 + CHUNK; e += 256){
    int seg = typ[e] * NN + dst[e];
    atomicAdd(&h[seg >> SHIFT], 1u);
  }
  __syncthreads();
  for (int g = t; g < GG; g += 256) Hist[(size_t)b * GG + g] = h[g];
}

__global__ __launch_bounds__(1024) void k_base(const u32* __restrict__ Hist, u32* __restrict__ Base,
                                               u32* __restrict__ rowp){
  __shared__ u32 tot[GG];
  int t = threadIdx.x;
  if (t < GG){
    u32 s = 0;
    for (int b = 0; b < NBLK; b++) s += Hist[(size_t)b * GG + t];
    tot[t] = s;
  }
  __syncthreads();
  if (t == 0){
    u32 acc = 0;
    for (int g = 0; g < GG; g++){ u32 c = tot[g]; Base[g] = acc; acc += c; }
    Base[GG] = acc;      // == EE
    rowp[NT] = EE;
  }
}

__global__ __launch_bounds__(512) void k_off(const u32* __restrict__ Hist, const u32* __restrict__ Base,
                                             u32* __restrict__ Off){
  __shared__ u32 v[NBLK];
  int g = blockIdx.x, t = threadIdx.x;     // t == phase-1 block id
  v[t] = Hist[(size_t)t * GG + g];
  __syncthreads();
  if (t == 0){
    u32 acc = Base[g];
    for (int b = 0; b < NBLK; b++){ u32 c = v[b]; v[b] = acc; acc += c; }
  }
  __syncthreads();
  Off[(size_t)g * NBLK + t] = v[t];
}

__global__ __launch_bounds__(256) void k_fill(const int* __restrict__ src, const int* __restrict__ dst,
                                              const int* __restrict__ typ, const u32* __restrict__ Off,
                                              u32* __restrict__ bstore){
  __shared__ u32 cur[GG];
  int b = blockIdx.x, t = threadIdx.x;
  for (int g = t; g < GG; g += 256) cur[g] = Off[(size_t)g * NBLK + b];
  __syncthreads();
  int e0 = b * CHUNK;
  for (int e = e0 + t; e < e0 + CHUNK; e += 256){
    int seg = typ[e] * NN + dst[e];
    u32 pos = atomicAdd(&cur[seg >> SHIFT], 1u);   // LDS atomic; exact reserved range, no overflow
    bstore[pos] = ((u32)(seg & 511) << 17) | (u32)src[e];
  }
}

__global__ __launch_bounds__(256) void k_sortD(const u32* __restrict__ bstore, const u32* __restrict__ Base,
                                               u32* __restrict__ rowp, u32* __restrict__ edges){
  __shared__ u32 ent[BMAX];
  __shared__ u32 binc[512], bexc[512];
  int g = blockIdx.x, t = threadIdx.x;
  u32 base = Base[g];
  u32 cnt = Base[g + 1] - base;
  if (cnt > (u32)BMAX) cnt = (u32)BMAX;    // distribution gives 11-sigma headroom
  for (int i = t; i < 512; i += 256) binc[i] = 0u;
  __syncthreads();
  for (u32 i = t; i < cnt; i += 256){
    u32 v = bstore[base + i];
    ent[i] = v;
    atomicAdd(&binc[v >> 17], 1u);
  }
  __syncthreads();
  if (t == 0){
    u32 acc = 0;
    #pragma unroll 8
    for (int s = 0; s < 512; s++){ u32 c = binc[s]; bexc[s] = acc; binc[s] = acc; acc += c; }
  }
  __syncthreads();
  for (int s = t; s < 512; s += 256){
    int seg = g * 512 + s;
    if (seg < NT) rowp[seg] = base + bexc[s];
  }
  __syncthreads();
  for (u32 i = t; i < cnt; i += 256){
    u32 v = ent[i];
    u32 p = atomicAdd(&binc[v >> 17], 1u);
    edges[base + p] = v & 0x1FFFFu;
  }
}

// ---------------- weight repack (both layers): pwB[l][mat][out][c] bf16 ----------------
// mats 0-3 Q r0-3 ; 4-7 K ; 8-11 V ; 12 W_self ; 13-16 Wcat r0-3
__global__ __launch_bounds__(256) void k_repackbf(const float* __restrict__ WQ, const float* __restrict__ WK,
                                                  const float* __restrict__ WV, const float* __restrict__ Wcat,
                                                  const float* __restrict__ Wself, u16* __restrict__ pwB){
  int t = blockIdx.x * 256 + threadIdx.x;
  if (t >= 2 * 17 * 4096) return;
  int l = t / (17 * 4096), rem = t % (17 * 4096);
  int mat = rem >> 12, idx = rem & 4095;
  int out = idx >> 6, c = idx & 63;
  float v;
  if (mat < 12){
    int kind = mat >> 2, r = mat & 3;
    int h = out >> 3, d = out & 7;
    const float* Wsrc = (kind == 0) ? WQ : (kind == 1) ? WK : WV;
    v = Wsrc[((((l * RRR + r) * HHH + h) * 64) + c) * 8 + d];
  } else if (mat == 12){
    v = Wself[(l * 64 + c) * 64 + out];
  } else {
    int r = mat - 13;
    v = Wcat[(((l * RRR + r) * 64) + c) * 64 + out];
  }
  pwB[t] = f2bf(v);
}

// ---------------- MFMA helpers ----------------
// A-frag (16x32): row = lane&15, k = (lane>>4)*8 + j (8 consecutive)
// B-frag (32x16): col = lane&15, k = (lane>>4)*8 + j  -> read from [out][c] layout
// D (16x16): col = lane&15, row = (lane>>4)*4 + reg

// ---------------- Q,K,V MFMA GEMM for one relation ----------------
__global__ __launch_bounds__(256) void k_qkv(const float* __restrict__ x,
                                             const u16* __restrict__ pwQ, const u16* __restrict__ pwK,
                                             const u16* __restrict__ pwV,
                                             u16* __restrict__ Qr, u32* __restrict__ kvp){
  __shared__ u16 xa[64][72];
  __shared__ u16 wt[3][64][72];
  int t = threadIdx.x;
  int n0 = blockIdx.x * 64;
  { // stage x -> bf16
    int row = t >> 2, c0 = (t & 3) * 16;
    int n = n0 + row;
    float4 v0 = {}, v1 = {}, v2 = {}, v3 = {};
    if (n < NN){
      const float4* xp = (const float4*)(x + (size_t)n * 64 + c0);
      v0 = xp[0]; v1 = xp[1]; v2 = xp[2]; v3 = xp[3];
    }
    ushort4* dp = (ushort4*)&xa[row][c0];
    dp[0] = make_ushort4(f2bf(v0.x), f2bf(v0.y), f2bf(v0.z), f2bf(v0.w));
    dp[1] = make_ushort4(f2bf(v1.x), f2bf(v1.y), f2bf(v1.z), f2bf(v1.w));
    dp[2] = make_ushort4(f2bf(v2.x), f2bf(v2.y), f2bf(v2.z), f2bf(v2.w));
    dp[3] = make_ushort4(f2bf(v3.x), f2bf(v3.y), f2bf(v3.z), f2bf(v3.w));
  }
  { // stage weights (already bf16, [out][c])
    const u32* p0 = (const u32*)pwQ;
    const u32* p1 = (const u32*)pwK;
    const u32* p2 = (const u32*)pwV;
    for (int idx = t; idx < 3 * 2048; idx += 256){
      int m = idx >> 11, rem = idx & 2047;
      int out = rem >> 5, cc = rem & 31;
      u32 w = (m == 0) ? p0[rem] : (m == 1) ? p1[rem] : p2[rem];
      *(u32*)&wt[m][out][cc * 2] = w;
    }
  }
  __syncthreads();
  int w = t >> 6, lane = t & 63;
  int ra = w * 16 + (lane & 15);
  int kg = (lane >> 4) * 8;
  int cb = lane & 15;
  int rb = (lane >> 4) * 4;
  bf16x8 a0 = *(const bf16x8*)&xa[ra][kg];
  bf16x8 a1 = *(const bf16x8*)&xa[ra][32 + kg];
  f32x4 z = {0.f, 0.f, 0.f, 0.f};
  { // Q
    f32x4 acc[4] = {z, z, z, z};
    #pragma unroll
    for (int t4 = 0; t4 < 4; t4++){
      bf16x8 b0 = *(const bf16x8*)&wt[0][t4 * 16 + cb][kg];
      bf16x8 b1 = *(const bf16x8*)&wt[0][t4 * 16 + cb][32 + kg];
      acc[t4] = __builtin_amdgcn_mfma_f32_16x16x32_bf16(a0, b0, acc[t4], 0, 0, 0);
      acc[t4] = __builtin_amdgcn_mfma_f32_16x16x32_bf16(a1, b1, acc[t4], 0, 0, 0);
    }
    #pragma unroll
    for (int t4 = 0; t4 < 4; t4++){
      #pragma unroll
      for (int i = 0; i < 4; i++){
        int n = n0 + w * 16 + rb + i;
        if (n < NN) Qr[(size_t)n * 64 + t4 * 16 + cb] = f2bf(acc[t4][i]);
      }
    }
  }
  { // K,V packed
    f32x4 ak[4] = {z, z, z, z};
    f32x4 av[4] = {z, z, z, z};
    #pragma unroll
    for (int t4 = 0; t4 < 4; t4++){
      bf16x8 bk0 = *(const bf16x8*)&wt[1][t4 * 16 + cb][kg];
      bf16x8 bk1 = *(const bf16x8*)&wt[1][t4 * 16 + cb][32 + kg];
      bf16x8 bv0 = *(const bf16x8*)&wt[2][t4 * 16 + cb][kg];
      bf16x8 bv1 = *(const bf16x8*)&wt[2][t4 * 16 + cb][32 + kg];
      ak[t4] = __builtin_amdgcn_mfma_f32_16x16x32_bf16(a0, bk0, ak[t4], 0, 0, 0);
      ak[t4] = __builtin_amdgcn_mfma_f32_16x16x32_bf16(a1, bk1, ak[t4], 0, 0, 0);
      av[t4] = __builtin_amdgcn_mfma_f32_16x16x32_bf16(a0, bv0, av[t4], 0, 0, 0);
      av[t4] = __builtin_amdgcn_mfma_f32_16x16x32_bf16(a1, bv1, av[t4], 0, 0, 0);
    }
    #pragma unroll
    for (int t4 = 0; t4 < 4; t4++){
      #pragma unroll
      for (int i = 0; i < 4; i++){
        int n = n0 + w * 16 + rb + i;
        if (n < NN) kvp[(size_t)n * 64 + t4 * 16 + cb] = (u32)f2bf(ak[t4][i]) | ((u32)f2bf(av[t4][i]) << 16);
      }
    }
  }
}

// ---------------- self MFMA GEMM (1 mat, u16 out) ----------------
__global__ __launch_bounds__(256) void k_self(const float* __restrict__ x, const u16* __restrict__ pwS,
                                              u16* __restrict__ outb){
  __shared__ u16 xa[64][72];
  __shared__ u16 wt[64][72];
  int t = threadIdx.x;
  int n0 = blockIdx.x * 64;
  {
    int row = t >> 2, c0 = (t & 3) * 16;
    int n = n0 + row;
    float4 v0 = {}, v1 = {}, v2 = {}, v3 = {};
    if (n < NN){
      const float4* xp = (const float4*)(x + (size_t)n * 64 + c0);
      v0 = xp[0]; v1 = xp[1]; v2 = xp[2]; v3 = xp[3];
    }
    ushort4* dp = (ushort4*)&xa[row][c0];
    dp[0] = make_ushort4(f2bf(v0.x), f2bf(v0.y), f2bf(v0.z), f2bf(v0.w));
    dp[1] = make_ushort4(f2bf(v1.x), f2bf(v1.y), f2bf(v1.z), f2bf(v1.w));
    dp[2] = make_ushort4(f2bf(v2.x), f2bf(v2.y), f2bf(v2.z), f2bf(v2.w));
    dp[3] = make_ushort4(f2bf(v3.x), f2bf(v3.y), f2bf(v3.z), f2bf(v3.w));
  }
  {
    const u32* p0 = (const u32*)pwS;
    for (int idx = t; idx < 2048; idx += 256){
      int out = idx >> 5, cc = idx & 31;
      *(u32*)&wt[out][cc * 2] = p0[idx];
    }
  }
  __syncthreads();
  int w = t >> 6, lane = t & 63;
  int ra = w * 16 + (lane & 15);
  int kg = (lane >> 4) * 8;
  int cb = lane & 15;
  int rb = (lane >> 4) * 4;
  bf16x8 a0 = *(const bf16x8*)&xa[ra][kg];
  bf16x8 a1 = *(const bf16x8*)&xa[ra][32 + kg];
  f32x4 z = {0.f, 0.f, 0.f, 0.f};
  f32x4 acc[4] = {z, z, z, z};
  #pragma unroll
  for (int t4 = 0; t4 < 4; t4++){
    bf16x8 b0 = *(const bf16x8*)&wt[t4 * 16 + cb][kg];
    bf16x8 b1 = *(const bf16x8*)&wt[t4 * 16 + cb][32 + kg];
    acc[t4] = __builtin_amdgcn_mfma_f32_16x16x32_bf16(a0, b0, acc[t4], 0, 0, 0);
    acc[t4] = __builtin_amdgcn_mfma_f32_16x16x32_bf16(a1, b1, acc[t4], 0, 0, 0);
  }
  #pragma unroll
  for (int t4 = 0; t4 < 4; t4++){
    #pragma unroll
    for (int i = 0; i < 4; i++){
      int n = n0 + w * 16 + rb + i;
      if (n < NN) outb[(size_t)n * 64 + t4 * 16 + cb] = f2bf(acc[t4][i]);
    }
  }
}

// ---------------- edge gather: lane-parallel adjacency + 4-deep unroll ----------------
__global__ __launch_bounds__(256) void k_gather(const u32* __restrict__ edges, const u32* __restrict__ rowpR,
                                                const u32* __restrict__ kvp, const u16* __restrict__ Qr,
                                                u16* __restrict__ Sr, float* __restrict__ alphaR){
  int wid = threadIdx.x >> 6, lane = threadIdx.x & 63;
  int n = blockIdx.x * 4 + wid;
  float q = bf2f(Qr[(size_t)n * 64 + lane]);
  u32 beg = rowpR[n], end = rowpR[n + 1];
  float sa = 0.f, aa = 0.f;
  const float inv_sqrt_d = 0.35355339059327373f;
  for (u32 base = beg; base < end; base += 64){
    u32 cnt = (end - base < 64u) ? (end - base) : 64u;
    u32 eidx = (base + (u32)lane < end) ? edges[base + lane] : 0u;
    u32 j = 0;
    for (; j + 4 <= cnt; j += 4){
      int s0 = __shfl((int)eidx, (int)j);
      int s1 = __shfl((int)eidx, (int)j + 1);
      int s2 = __shfl((int)eidx, (int)j + 2);
      int s3 = __shfl((int)eidx, (int)j + 3);
      u32 w0 = kvp[(size_t)s0 * 64 + lane];
      u32 w1 = kvp[(size_t)s1 * 64 + lane];
      u32 w2 = kvp[(size_t)s2 * 64 + lane];
      u32 w3 = kvp[(size_t)s3 * 64 + lane];
      float p0 = q * bf2f((u16)(w0 & 0xFFFFu));
      float p1 = q * bf2f((u16)(w1 & 0xFFFFu));
      float p2 = q * bf2f((u16)(w2 & 0xFFFFu));
      float p3 = q * bf2f((u16)(w3 & 0xFFFFu));
      p0 += __shfl_xor(p0, 1); p1 += __shfl_xor(p1, 1); p2 += __shfl_xor(p2, 1); p3 += __shfl_xor(p3, 1);
      p0 += __shfl_xor(p0, 2); p1 += __shfl_xor(p1, 2); p2 += __shfl_xor(p2, 2); p3 += __shfl_xor(p3, 2);
      p0 += __shfl_xor(p0, 4); p1 += __shfl_xor(p1, 4); p2 += __shfl_xor(p2, 4); p3 += __shfl_xor(p3, 4);
      float e0 = p0 * inv_sqrt_d; e0 = (e0 > 0.f) ? e0 : 0.01f * e0;
      float e1 = p1 * inv_sqrt_d; e1 = (e1 > 0.f) ? e1 : 0.01f * e1;
      float e2 = p2 * inv_sqrt_d; e2 = (e2 > 0.f) ? e2 : 0.01f * e2;
      float e3 = p3 * inv_sqrt_d; e3 = (e3 > 0.f) ? e3 : 0.01f * e3;
      aa += (e0 + e1) + (e2 + e3);
      sa += (bf2f((u16)(w0 >> 16)) + bf2f((u16)(w1 >> 16))) +
            (bf2f((u16)(w2 >> 16)) + bf2f((u16)(w3 >> 16)));
    }
    for (; j < cnt; ++j){
      int s = __shfl((int)eidx, (int)j);
      u32 w = kvp[(size_t)s * 64 + lane];
      float p = q * bf2f((u16)(w & 0xFFFFu));
      p += __shfl_xor(p, 1);
      p += __shfl_xor(p, 2);
      p += __shfl_xor(p, 4);
      float e = p * inv_sqrt_d;
      e = (e > 0.f) ? e : 0.01f * e;
      aa += e;
      sa += bf2f((u16)(w >> 16));
    }
  }
  Sr[(size_t)n * 64 + lane] = f2bf(sa);
  if ((lane & 7) == 0) alphaR[(size_t)n * 8 + (lane >> 3)] = aa;
}

// ---------------- column softmax stats over N per (r,h) ----------------
__global__ __launch_bounds__(256) void k_stats1(const float* __restrict__ alpha, float2* __restrict__ part){
  int col = blockIdx.x;
  int r = col >> 3, h = col & 7;
  int chunk = blockIdx.y;
  const int per = (NN + 31) / 32;
  int nbeg = chunk * per;
  int nend = nbeg + per; if (nend > NN) nend = NN;
  int t = threadIdx.x;
  float m = -1e30f, s = 0.f;
  for (int n = nbeg + t; n < nend; n += 256){
    float a = alpha[((size_t)r * NN + n) * 8 + h];
    if (a > m){ s *= expf(m - a); m = a; }
    s += expf(a - m);
  }
  __shared__ float sm[256], ss[256];
  sm[t] = m; ss[t] = s; __syncthreads();
  for (int off = 128; off > 0; off >>= 1){
    if (t < off){
      float m2 = sm[t + off], s2 = ss[t + off];
      float M = fmaxf(sm[t], m2);
      ss[t] = ss[t] * expf(sm[t] - M) + s2 * expf(m2 - M);
      sm[t] = M;
    }
    __syncthreads();
  }
  if (t == 0) part[col * 32 + chunk] = make_float2(sm[0], ss[0]);
}

__global__ void k_stats2(const float2* __restrict__ part, float2* __restrict__ fin){
  int col = threadIdx.x;
  if (col < 32){
    float M = -1e30f, S = 0.f;
    for (int i = 0; i < 32; i++){
      float2 p = part[col * 32 + i];
      float Mn = fmaxf(M, p.x);
      S = S * expf(M - Mn) + p.y * expf(p.x - Mn);
      M = Mn;
    }
    fin[col] = make_float2(M, 1.f / S);
  }
}

// ---------------- message MFMA GEMM with fused alpha apply ----------------
__global__ __launch_bounds__(256) void k_msg(const u16* __restrict__ S, const float* __restrict__ alpha,
                                             const float2* __restrict__ fin, const u16* __restrict__ pwCat,
                                             u16* __restrict__ stacked){
  __shared__ u16 xa[64][72];
  __shared__ u16 wt[64][72];
  int r = blockIdx.y;
  int t = threadIdx.x;
  int n0 = blockIdx.x * 64;
  { // stage A = (alpha ⊙ S) -> bf16
    int row = t >> 2, c0 = (t & 3) * 16;
    int n = n0 + row;
    int na = (n < NN) ? n : (NN - 1);
    int h0 = c0 >> 3;
    float2 f0 = fin[r * 8 + h0];
    float2 f1 = fin[r * 8 + h0 + 1];
    float a0 = alpha[((size_t)r * NN + na) * 8 + h0];
    float a1 = alpha[((size_t)r * NN + na) * 8 + h0 + 1];
    float w0 = expf(a0 - f0.x) * f0.y;
    float w1 = expf(a1 - f1.x) * f1.y;
    const u32* sp = (const u32*)(S + ((size_t)r * NN + na) * 64 + c0);
    #pragma unroll
    for (int jj = 0; jj < 8; jj++){
      u32 bts = sp[jj];
      float wm = (jj < 4) ? w0 : w1;
      ushort2 o;
      o.x = f2bf(bf2f((u16)(bts & 0xFFFFu)) * wm);
      o.y = f2bf(bf2f((u16)(bts >> 16)) * wm);
      *(ushort2*)&xa[row][c0 + jj * 2] = o;
    }
  }
  {
    const u32* p0 = (const u32*)(pwCat + (size_t)r * 4096);
    for (int idx = t; idx < 2048; idx += 256){
      int out = idx >> 5, cc = idx & 31;
      *(u32*)&wt[out][cc * 2] = p0[idx];
    }
  }
  __syncthreads();
  int w = t >> 6, lane = t & 63;
  int ra = w * 16 + (lane & 15);
  int kg = (lane >> 4) * 8;
  int cb = lane & 15;
  int rb = (lane >> 4) * 4;
  bf16x8 a0 = *(const bf16x8*)&xa[ra][kg];
  bf16x8 a1 = *(const bf16x8*)&xa[ra][32 + kg];
  f32x4 z = {0.f, 0.f, 0.f, 0.f};
  f32x4 acc[4] = {z, z, z, z};
  #pragma unroll
  for (int t4 = 0; t4 < 4; t4++){
    bf16x8 b0 = *(const bf16x8*)&wt[t4 * 16 + cb][kg];
    bf16x8 b1 = *(const bf16x8*)&wt[t4 * 16 + cb][32 + kg];
    acc[t4] = __builtin_amdgcn_mfma_f32_16x16x32_bf16(a0, b0, acc[t4], 0, 0, 0);
    acc[t4] = __builtin_amdgcn_mfma_f32_16x16x32_bf16(a1, b1, acc[t4], 0, 0, 0);
  }
  #pragma unroll
  for (int t4 = 0; t4 < 4; t4++){
    #pragma unroll
    for (int i = 0; i < 4; i++){
      int n = n0 + w * 16 + rb + i;
      if (n < NN) stacked[((size_t)r * NN + n) * 64 + t4 * 16 + cb] = f2bf(acc[t4][i]);
    }
  }
}

// ---------------- semantic attn + gelu + residual + LN (streaming + shfl) ----------------
__global__ __launch_bounds__(256) void k_final(const u16* __restrict__ stacked, const u16* __restrict__ selfb,
                                               const float* __restrict__ xin,
                                               const float* __restrict__ semw, const float* __restrict__ semb,
                                               const float* __restrict__ lng, const float* __restrict__ lnb,
                                               float* __restrict__ xout){
  int t = threadIdx.x;
  int wid = t >> 6, lane = t & 63;
  int n = blockIdx.x * 4 + wid;
  float st[4];
  #pragma unroll
  for (int r = 0; r < 4; r++) st[r] = bf2f(stacked[((size_t)r * NN + n) * 64 + lane]);
  float sw = semw[lane];
  float lg[4];
  #pragma unroll
  for (int r = 0; r < 4; r++){
    float p = st[r] * sw;
    #pragma unroll
    for (int o = 1; o < 64; o <<= 1) p += __shfl_xor(p, o);
    lg[r] = p + semb[0];
  }
  float mx = fmaxf(fmaxf(lg[0], lg[1]), fmaxf(lg[2], lg[3]));
  float e0 = expf(lg[0] - mx), e1 = expf(lg[1] - mx), e2 = expf(lg[2] - mx), e3 = expf(lg[3] - mx);
  float inv = 1.f / (e0 + e1 + e2 + e3);
  float agg = (e0 * st[0] + e1 * st[1] + e2 * st[2] + e3 * st[3]) * inv;
  float pre = bf2f(selfb[(size_t)n * 64 + lane]) + agg;
  float ge = 0.5f * pre * (1.f + erff(pre * 0.70710678118654752f));
  float y = xin[(size_t)n * 64 + lane] + ge;
  float mu = y;
  #pragma unroll
  for (int o = 1; o < 64; o <<= 1) mu += __shfl_xor(mu, o);
  mu *= (1.f / 64.f);
  float d = y - mu;
  float vv = d * d;
  #pragma unroll
  for (int o = 1; o < 64; o <<= 1) vv += __shfl_xor(vv, o);
  vv *= (1.f / 64.f);
  xout[(size_t)n * 64 + lane] = d * rsqrtf(vv + 1e-5f) * lng[lane] + lnb[lane];
}

extern "C" void kernel_launch(void* const* d_in, const int* in_sizes, int n_in,
                              void* d_out, int out_size, void* d_ws, size_t ws_size,
                              hipStream_t stream){
  const float* x0    = (const float*)d_in[0];
  const int*   eidx  = (const int*)d_in[1];
  const int*   etyp  = (const int*)d_in[2];
  const float* WQ    = (const float*)d_in[3];
  const float* WK    = (const float*)d_in[4];
  const float* WV    = (const float*)d_in[5];
  const float* Wcat  = (const float*)d_in[6];
  const float* semw  = (const float*)d_in[7];
  const float* semb  = (const float*)d_in[8];
  const float* Wself = (const float*)d_in[9];
  const float* lng   = (const float*)d_in[10];
  const float* lnb   = (const float*)d_in[11];
  float* out = (float*)d_out;
  char* ws = (char*)d_ws;

  const int* srcArr = eidx;        // edge_index row 0 = src (j)
  const int* dstArr = eidx + EE;   // row 1 = dst (i)

  u32*  kvp      = (u32*)(ws + OFF_KV);
  u16*  selfb    = (u16*)(ws + OFF_KV);    // aliases kvp after last gather
  u16*  Qb       = (u16*)(ws + OFF_Q);
  u16*  stackedB = (u16*)(ws + OFF_Q);     // aliases dead Q after gathers
  u16*  Sb       = (u16*)(ws + OFF_S);
  float* alphaB  = (float*)(ws + OFF_AL);
  u16*  pwB      = (u16*)(ws + OFF_PW);
  float2* part   = (float2*)(ws + OFF_PART);
  float2* fin    = (float2*)(ws + OFF_FIN);
  u32* rowp   = (u32*)(ws + OFF_ROWP);
  u32* edges  = (u32*)(ws + OFF_EDG);
  u32* bstore = (u32*)(ws + OFF_BSTORE);   // CSR temps alias S
  u32* Hist   = (u32*)(ws + OFF_HIST);
  u32* Off    = (u32*)(ws + OFF_OFFA);
  u32* Base   = (u32*)(ws + OFF_BASE);

  // ---- CSR segmented by (relation, dst): no-atomic two-pass partition ----
  k_histA<<<NBLK, 256, 0, stream>>>(dstArr, etyp, Hist);
  k_base<<<1, 1024, 0, stream>>>(Hist, Base, rowp);
  k_off<<<GG, 512, 0, stream>>>(Hist, Base, Off);
  k_fill<<<NBLK, 256, 0, stream>>>(srcArr, dstArr, etyp, Off, bstore);
  k_sortD<<<GG, 256, 0, stream>>>(bstore, Base, rowp, edges);
  k_repackbf<<<(2 * 17 * 4096 + 255) / 256, 256, 0, stream>>>(WQ, WK, WV, Wcat, Wself, pwB);

  for (int l = 0; l < 2; l++){
    const float* xcur = (l == 0) ? x0 : out;
    const u16* pwL = pwB + (size_t)l * 17 * 4096;
    for (int r = 0; r < 4; r++){
      k_qkv<<<1563, 256, 0, stream>>>(xcur, pwL + (size_t)r * 4096, pwL + (size_t)(4 + r) * 4096,
                                      pwL + (size_t)(8 + r) * 4096, Qb + (size_t)r * NN * 64, kvp);
      k_gather<<<NN / 4, 256, 0, stream>>>(edges, rowp + (size_t)r * NN, kvp,
                                           Qb + (size_t)r * NN * 64,
                                           Sb + (size_t)r * NN * 64,
                                           alphaB + (size_t)r * NN * 8);
    }
    k_self<<<1563, 256, 0, stream>>>(xcur, pwL + (size_t)12 * 4096, selfb);
    k_stats1<<<dim3(32, 32), 256, 0, stream>>>(alphaB, part);
    k_stats2<<<1, 64, 0, stream>>>(part, fin);
    k_msg<<<dim3(1563, 4), 256, 0, stream>>>(Sb, alphaB, fin, pwL + (size_t)13 * 4096, stackedB);
    k_final<<<NN / 4, 256, 0, stream>>>(stackedB, selfb, xcur,
                                        semw + l * 64, semb + l, lng + l * 64, lnb + l * 64, out);
  }
  (void)in_sizes; (void)n_in; (void)out_size; (void)ws_size;
}